// Round 1
// 345.706 us; speedup vs baseline: 1.4018x; 1.4018x over previous
//
#include <hip/hip_runtime.h>
#include <hip/hip_bf16.h>

// B=64, T=21, E=H=512, V=10000. fp32 in/out.
// gates = x@W_ih^T + h@W_hh^T + (b_ih+b_hh); i,f,g,o; out = h@W_lin^T + b_lin.

#define NB 64
#define NT 21
#define NE 512
#define NH 512
#define NV 10000
#define G4 2048

typedef __attribute__((ext_vector_type(8))) short bf16x8;
typedef __attribute__((ext_vector_type(4))) float f32x4;
typedef __attribute__((ext_vector_type(4))) unsigned short u16x4;

// ---- workspace layout (bytes) ----
#define OFF_WIH_HI   0UL
#define OFF_WIH_LO   2097152UL
#define OFF_WHH_HI   4194304UL
#define OFF_WHH_LO   6291456UL
#define OFF_WLIN_HI  8388608UL     // 10112*512*2
#define OFF_XSEQ_HI  18743296UL    // 1408*512*2
#define OFF_XSEQ_LO  20185088UL
#define OFF_BIAS     21626880UL    // 2048*4
#define OFF_XIH      21635072UL    // 21*64*2048*4
#define OFF_GHH      32645120UL    // 2 x 64*512 bf16 h-hi (PRE-SWIZZLED chunk layout)
#define OFF_GHL      32776192UL    // 2 x 64*512 bf16 h-lo (PRE-SWIZZLED chunk layout)
#define OFF_C        32907264UL    // (unused now; c-state lives in registers)
#define OFF_HBUF     33038336UL    // 20*64*512 bf16
#define OFF_FLG      34349056UL    // per-step barrier counters
// end 34,351,616 B

__device__ inline unsigned short f2bf(float f) {
    unsigned int u = __float_as_uint(f);
    unsigned int r = u + 0x7FFFu + ((u >> 16) & 1u);
    return (unsigned short)(r >> 16);
}
__device__ inline float bf2f(unsigned short s) {
    return __uint_as_float(((unsigned int)s) << 16);
}

__device__ __forceinline__ void gl_lds16(const unsigned short* g, unsigned short* l) {
    auto gp = (const __attribute__((address_space(1))) unsigned int*)(unsigned long long)(const void*)g;
    auto lp = (__attribute__((address_space(3))) unsigned int*)(unsigned int)(unsigned long long)(void*)l;
    __builtin_amdgcn_global_load_lds(gp, lp, 16, 0, 0);
}

// ---------------- prep (vectorized x4) ----------------
__global__ __launch_bounds__(256) void prep_kernel(
    const float* __restrict__ features, const float* __restrict__ cap,
    const float* __restrict__ W_ih, const float* __restrict__ W_hh,
    const float* __restrict__ b_ih, const float* __restrict__ b_hh,
    const float* __restrict__ W_lin, unsigned char* __restrict__ ws)
{
    const int idx = blockIdx.x * 256 + threadIdx.x;
    unsigned short* wih_hi = (unsigned short*)(ws + OFF_WIH_HI);
    unsigned short* wih_lo = (unsigned short*)(ws + OFF_WIH_LO);
    unsigned short* whh_hi = (unsigned short*)(ws + OFF_WHH_HI);
    unsigned short* whh_lo = (unsigned short*)(ws + OFF_WHH_LO);
    unsigned short* wlin_hi = (unsigned short*)(ws + OFF_WLIN_HI);
    unsigned short* xs_hi = (unsigned short*)(ws + OFF_XSEQ_HI);
    unsigned short* xs_lo = (unsigned short*)(ws + OFF_XSEQ_LO);
    float* bias = (float*)(ws + OFF_BIAS);

    if (idx < 262144) {
        const int i4 = idx * 4;
        float4 w = *(const float4*)(W_ih + i4);
        u16x4 hi, lo;
        hi.x = f2bf(w.x); lo.x = f2bf(w.x - bf2f(hi.x));
        hi.y = f2bf(w.y); lo.y = f2bf(w.y - bf2f(hi.y));
        hi.z = f2bf(w.z); lo.z = f2bf(w.z - bf2f(hi.z));
        hi.w = f2bf(w.w); lo.w = f2bf(w.w - bf2f(hi.w));
        *(u16x4*)(wih_hi + i4) = hi;
        *(u16x4*)(wih_lo + i4) = lo;
    } else if (idx < 524288) {
        const int i4 = (idx - 262144) * 4;
        float4 w = *(const float4*)(W_hh + i4);
        u16x4 hi, lo;
        hi.x = f2bf(w.x); lo.x = f2bf(w.x - bf2f(hi.x));
        hi.y = f2bf(w.y); lo.y = f2bf(w.y - bf2f(hi.y));
        hi.z = f2bf(w.z); lo.z = f2bf(w.z - bf2f(hi.z));
        hi.w = f2bf(w.w); lo.w = f2bf(w.w - bf2f(hi.w));
        *(u16x4*)(whh_hi + i4) = hi;
        *(u16x4*)(whh_lo + i4) = lo;
    } else if (idx < 1804288) {
        const int i4 = (idx - 524288) * 4;
        float4 w = *(const float4*)(W_lin + i4);
        u16x4 hi;
        hi.x = f2bf(w.x); hi.y = f2bf(w.y); hi.z = f2bf(w.z); hi.w = f2bf(w.w);
        *(u16x4*)(wlin_hi + i4) = hi;
    } else if (idx < 1976320) {
        const int i4 = (idx - 1804288) * 4;
        const int e = i4 & 511;
        const int b = (i4 >> 9) & 63;
        const int t = i4 >> 15;
        float4 x = (t == 0) ? *(const float4*)(features + b * NE + e)
                            : *(const float4*)(cap + b * (NT * NE) + (t - 1) * NE + e);
        u16x4 hi, lo;
        hi.x = f2bf(x.x); lo.x = f2bf(x.x - bf2f(hi.x));
        hi.y = f2bf(x.y); lo.y = f2bf(x.y - bf2f(hi.y));
        hi.z = f2bf(x.z); lo.z = f2bf(x.z - bf2f(hi.z));
        hi.w = f2bf(x.w); lo.w = f2bf(x.w - bf2f(hi.w));
        *(u16x4*)(xs_hi + i4) = hi;
        *(u16x4*)(xs_lo + i4) = lo;
    } else if (idx < 1976832) {
        const int j = (idx - 1976320) * 4;
        float4 a = *(const float4*)(b_ih + j);
        float4 b = *(const float4*)(b_hh + j);
        *(float4*)(bias + j) = make_float4(a.x + b.x, a.y + b.y, a.z + b.z, a.w + b.w);
    }
}

// ---------------- phase A: Xih = Xseq @ W_ih^T + bias, hi/lo 3-pass, tiled ----------------
__global__ __launch_bounds__(256) void gemm_a_kernel(unsigned char* __restrict__ ws)
{
    __shared__ unsigned short Ah[2][4096], Al[2][4096], Bh[2][4096], Bl[2][4096];
    const int tid = threadIdx.x;
    const int lane = tid & 63, wv = tid >> 6;
    const int mf = lane & 15, kg = lane >> 4;
    const int mw = (wv >> 1) * 64, nw = (wv & 1) * 64;
    const int m0 = blockIdx.y * 128, n0 = blockIdx.x * 128;

    const unsigned short* __restrict__ xh = (const unsigned short*)(ws + OFF_XSEQ_HI);
    const unsigned short* __restrict__ xl = (const unsigned short*)(ws + OFF_XSEQ_LO);
    const unsigned short* __restrict__ wh = (const unsigned short*)(ws + OFF_WIH_HI);
    const unsigned short* __restrict__ wl = (const unsigned short*)(ws + OFF_WIH_LO);
    const float* __restrict__ bias = (const float*)(ws + OFF_BIAS);
    float* __restrict__ xih = (float*)(ws + OFF_XIH);

    f32x4 acc[4][4];
#pragma unroll
    for (int i = 0; i < 4; i++)
#pragma unroll
        for (int j = 0; j < 4; j++) acc[i][j] = (f32x4){0.f, 0.f, 0.f, 0.f};

    auto stage = [&](int buf, int k0) {
#pragma unroll
        for (int h = 0; h < 2; ++h) {
            int s = h * 256 + tid;
            int r = s >> 2, ks = (s & 3) * 8;
            gl_lds16(xh + (size_t)(m0 + r) * 512 + k0 + ks, &Ah[buf][s * 8]);
            gl_lds16(xl + (size_t)(m0 + r) * 512 + k0 + ks, &Al[buf][s * 8]);
            gl_lds16(wh + (size_t)(n0 + r) * 512 + k0 + ks, &Bh[buf][s * 8]);
            gl_lds16(wl + (size_t)(n0 + r) * 512 + k0 + ks, &Bl[buf][s * 8]);
        }
    };

    stage(0, 0);
    for (int kt = 0; kt < 16; ++kt) {
        __syncthreads();
        const int cur = kt & 1;
        if (kt < 15) stage(cur ^ 1, (kt + 1) * 32);
        bf16x8 ah[4], al[4], bh[4], bl[4];
#pragma unroll
        for (int i = 0; i < 4; i++) {
            ah[i] = *(const bf16x8*)&Ah[cur][(mw + i * 16 + mf) * 32 + kg * 8];
            al[i] = *(const bf16x8*)&Al[cur][(mw + i * 16 + mf) * 32 + kg * 8];
            bh[i] = *(const bf16x8*)&Bh[cur][(nw + i * 16 + mf) * 32 + kg * 8];
            bl[i] = *(const bf16x8*)&Bl[cur][(nw + i * 16 + mf) * 32 + kg * 8];
        }
#pragma unroll
        for (int i = 0; i < 4; i++)
#pragma unroll
            for (int j = 0; j < 4; j++) {
                acc[i][j] = __builtin_amdgcn_mfma_f32_16x16x32_bf16(ah[i], bh[j], acc[i][j], 0, 0, 0);
                acc[i][j] = __builtin_amdgcn_mfma_f32_16x16x32_bf16(ah[i], bl[j], acc[i][j], 0, 0, 0);
                acc[i][j] = __builtin_amdgcn_mfma_f32_16x16x32_bf16(al[i], bh[j], acc[i][j], 0, 0, 0);
            }
    }
#pragma unroll
    for (int i = 0; i < 4; i++)
#pragma unroll
        for (int j = 0; j < 4; j++) {
            const int col = n0 + nw + j * 16 + mf;
            const float bb = bias[col];
#pragma unroll
            for (int r = 0; r < 4; r++) {
                const int R = m0 + mw + i * 16 + kg * 4 + r;
                if (R < NT * NB) xih[(size_t)R * G4 + col] = acc[i][j][r] + bb;
            }
        }
}

// ---------------- phase B: persistent LSTM ----------------
// 32 blocks x 512 thr. 8 waves = 4 gate quadrants x 2 row-halves; each wave
// does the FULL K=512 with W_hh hi+lo fragments register-resident (128 VGPR),
// so accumulators are complete gate sums -> no K-split LDS reduction.
// Cross-step h: hi AND lo both stored pre-swizzled in global, DMA'd linearly
// into LDS (conflict-free image); counted vmcnt(8)+s_barrier releases the hi
// half early so hi-pass MFMAs overlap the lo-half DMA stream.
// c-state lives in 2 registers/thread; xih gate inputs prefetched into 8
// registers BEFORE the inter-block barrier (registers survive buffer_inv).
// Barrier: relaxed agent fetch_add arrive + relaxed agent LOAD poll.
__global__ __launch_bounds__(512, 2) void lstm_persistent(unsigned char* __restrict__ ws)
{
    __shared__ unsigned short Hhi[64 * 512];   // 64 KB h-hi image
    __shared__ unsigned short Hlo[64 * 512];   // 64 KB h-lo image
    __shared__ float glf[4096];                // 16 KB gate values
    const int tid = threadIdx.x;
    const int lane = tid & 63, wv = tid >> 6;
    const int mf = lane & 15, kg = lane >> 4;
    const int q = wv & 3;        // gate quadrant
    const int mh = wv >> 2;      // row half (rows mh*32 .. mh*32+31)
    const int bc = blockIdx.x;

    unsigned short* __restrict__ ghh = (unsigned short*)(ws + OFF_GHH);
    unsigned short* __restrict__ ghl = (unsigned short*)(ws + OFF_GHL);
    const unsigned short* __restrict__ whh_hi = (const unsigned short*)(ws + OFF_WHH_HI);
    const unsigned short* __restrict__ whh_lo = (const unsigned short*)(ws + OFF_WHH_LO);
    const float* __restrict__ xih_base = (const float*)(ws + OFF_XIH);
    unsigned short* __restrict__ hbuf = (unsigned short*)(ws + OFF_HBUF);
    unsigned int* __restrict__ ctr = (unsigned int*)(ws + OFF_FLG);

    // ---- preload W_hh hi+lo fragments, full K: cols q*512+bc*16+mf ----
    bf16x8 bh[16], blo[16];
#pragma unroll
    for (int j = 0; j < 16; ++j) {
        const size_t off = (size_t)(q * 512 + bc * 16 + mf) * 512 + j * 32 + kg * 8;
        bh[j] = *(const bf16x8*)(whh_hi + off);
        blo[j] = *(const bf16x8*)(whh_lo + off);
    }

    // ---- per-thread cell mapping (2 cells/thread) + register state ----
    const int row0 = tid >> 4;          // cc=0 row in [0,32)
    const int row1 = row0 + 32;         // cc=1 row in [32,64)
    const int ci = tid & 15;
    const int c = bc * 16 + ci;
    const int jc = c >> 3;
    float creg[2] = {0.f, 0.f};

    float xp[8];
    auto load_xp = [&](int tt) {
        const float* __restrict__ xq = xih_base + (size_t)tt * NB * G4;
#pragma unroll
        for (int g = 0; g < 4; ++g) {
            xp[g]     = xq[row0 * G4 + g * 512 + c];
            xp[4 + g] = xq[row1 * G4 + g * 512 + c];
        }
    };
    load_xp(0);

    for (int t = 0; t < NT; ++t) {
        f32x4 acc[2];
        acc[0] = (f32x4){0.f, 0.f, 0.f, 0.f};
        acc[1] = (f32x4){0.f, 0.f, 0.f, 0.f};

        if (t > 0) {
            const int rd = (t + 1) & 1;
            const unsigned short* __restrict__ ghh_r = ghh + rd * (NB * NH);
            const unsigned short* __restrict__ ghl_r = ghl + rd * (NB * NH);
            // ---- bulk DMA: 8 hi insts then 8 lo insts per thread (128 KB) ----
#pragma unroll
            for (int i = 0; i < 8; ++i) {
                const int s = i * 512 + tid;
                gl_lds16(ghh_r + s * 8, &Hhi[s * 8]);
            }
#pragma unroll
            for (int i = 0; i < 8; ++i) {
                const int s = i * 512 + tid;
                gl_lds16(ghl_r + s * 8, &Hlo[s * 8]);
            }
            // hi half done (my 8 oldest of 16); barrier -> all waves' hi done
            asm volatile("s_waitcnt vmcnt(8)" ::: "memory");
            __builtin_amdgcn_s_barrier();
            // ---- hi passes: a_hi x (B_hi + B_lo), lo DMA still streaming ----
#pragma unroll
            for (int kt = 0; kt < 16; ++kt) {
                const int j = kt * 4 + kg;
#pragma unroll
                for (int m = 0; m < 2; ++m) {
                    const int row = mh * 32 + m * 16 + mf;
                    bf16x8 a_hi = *(const bf16x8*)&Hhi[(row * 64 + (j ^ (row & 7))) * 8];
                    acc[m] = __builtin_amdgcn_mfma_f32_16x16x32_bf16(a_hi, bh[kt], acc[m], 0, 0, 0);
                    acc[m] = __builtin_amdgcn_mfma_f32_16x16x32_bf16(a_hi, blo[kt], acc[m], 0, 0, 0);
                }
            }
            // lo half done everywhere
            asm volatile("s_waitcnt vmcnt(0)" ::: "memory");
            __builtin_amdgcn_s_barrier();
            // ---- lo pass: a_lo x B_hi ----
#pragma unroll
            for (int kt = 0; kt < 16; ++kt) {
                const int j = kt * 4 + kg;
#pragma unroll
                for (int m = 0; m < 2; ++m) {
                    const int row = mh * 32 + m * 16 + mf;
                    bf16x8 a_lo = *(const bf16x8*)&Hlo[(row * 64 + (j ^ (row & 7))) * 8];
                    acc[m] = __builtin_amdgcn_mfma_f32_16x16x32_bf16(a_lo, bh[kt], acc[m], 0, 0, 0);
                }
            }
        }

        // ---- full gate sums straight to LDS (no K-split reduction) ----
#pragma unroll
        for (int m = 0; m < 2; ++m) {
            const int row = mh * 32 + m * 16 + kg * 4;
#pragma unroll
            for (int r = 0; r < 4; ++r)
                glf[(q * 64 + row + r) * 16 + mf] = acc[m][r];
        }
        __syncthreads();

        // ---- LSTM cell: 1024 cells over 512 threads, c in registers ----
        unsigned short* __restrict__ ghh_w = ghh + (t & 1) * (NB * NH);
        unsigned short* __restrict__ ghl_w = ghl + (t & 1) * (NB * NH);
#pragma unroll
        for (int cc = 0; cc < 2; ++cc) {
            const int row = cc ? row1 : row0;
            const float gi = glf[(0 * 64 + row) * 16 + ci] + xp[cc * 4 + 0];
            const float gf = glf[(1 * 64 + row) * 16 + ci] + xp[cc * 4 + 1];
            const float gg = glf[(2 * 64 + row) * 16 + ci] + xp[cc * 4 + 2];
            const float go = glf[(3 * 64 + row) * 16 + ci] + xp[cc * 4 + 3];
            const float i_ = 1.f / (1.f + __expf(-gi));
            const float f_ = 1.f / (1.f + __expf(-gf));
            const float g_ = tanhf(gg);
            const float o_ = 1.f / (1.f + __expf(-go));
            const float c_new = f_ * creg[cc] + i_ * g_;
            creg[cc] = c_new;
            const float h_new = o_ * tanhf(c_new);
            const unsigned short hi = f2bf(h_new);
            const unsigned short lo = f2bf(h_new - bf2f(hi));
            // hi AND lo: swizzled chunk layout (chunk j' = j ^ (row&7))
            const int sw = row * 512 + ((jc ^ (row & 7)) << 3) + (c & 7);
            ghh_w[sw] = hi;
            ghl_w[sw] = lo;
            if (t >= 1)
                __builtin_nontemporal_store(hi, &hbuf[(t - 1) * (NB * NH) + row * NH + c]);
        }

        if (t < NT - 1) {
            load_xp(t + 1);    // prefetch next step's gate inputs into registers;
                               // drained by the syncthreads below, survives buffer_inv
            __syncthreads();   // all threads' stores + prefetch loads drained
            if (tid == 0) {
                __builtin_amdgcn_fence(__ATOMIC_RELEASE, "agent");  // one buffer_wbl2
                __hip_atomic_fetch_add(&ctr[t], 1u, __ATOMIC_RELAXED, __HIP_MEMORY_SCOPE_AGENT);
                while (__hip_atomic_load(&ctr[t], __ATOMIC_RELAXED, __HIP_MEMORY_SCOPE_AGENT) < 32u)
                    __builtin_amdgcn_s_sleep(1);
            }
            __syncthreads();
            __builtin_amdgcn_fence(__ATOMIC_ACQUIRE, "agent");      // one buffer_inv
        }
    }
}

// ---------------- phase C: Out = Hbuf[1280x512] @ W_lin^T + b_lin, tiled ----------------
__global__ __launch_bounds__(256) void gemm_c_kernel(
    unsigned char* __restrict__ ws, const float* __restrict__ b_lin, float* __restrict__ out)
{
    __shared__ unsigned short As[2][4096], Bs[2][4096];
    const int tid = threadIdx.x;
    const int lane = tid & 63, wv = tid >> 6;
    const int mf = lane & 15, kg = lane >> 4;
    const int mw = (wv >> 1) * 64, nw = (wv & 1) * 64;
    const int m0 = blockIdx.y * 128, n0 = blockIdx.x * 128;

    const unsigned short* __restrict__ hb = (const unsigned short*)(ws + OFF_HBUF);
    const unsigned short* __restrict__ wlin = (const unsigned short*)(ws + OFF_WLIN_HI);

    f32x4 acc[4][4];
#pragma unroll
    for (int i = 0; i < 4; i++)
#pragma unroll
        for (int j = 0; j < 4; j++) acc[i][j] = (f32x4){0.f, 0.f, 0.f, 0.f};

    auto stage = [&](int buf, int k0) {
#pragma unroll
        for (int h = 0; h < 2; ++h) {
            int s = h * 256 + tid;
            int r = s >> 2, ks = (s & 3) * 8;
            gl_lds16(hb + (size_t)(m0 + r) * 512 + k0 + ks, &As[buf][s * 8]);
            gl_lds16(wlin + (size_t)(n0 + r) * 512 + k0 + ks, &Bs[buf][s * 8]);
        }
    };

    stage(0, 0);
    for (int kt = 0; kt < 16; ++kt) {
        __syncthreads();
        const int cur = kt & 1;
        if (kt < 15) stage(cur ^ 1, (kt + 1) * 32);
        bf16x8 af[4], bf[4];
#pragma unroll
        for (int i = 0; i < 4; i++) {
            af[i] = *(const bf16x8*)&As[cur][(mw + i * 16 + mf) * 32 + kg * 8];
            bf[i] = *(const bf16x8*)&Bs[cur][(nw + i * 16 + mf) * 32 + kg * 8];
        }
#pragma unroll
        for (int i = 0; i < 4; i++)
#pragma unroll
            for (int j = 0; j < 4; j++)
                acc[i][j] = __builtin_amdgcn_mfma_f32_16x16x32_bf16(af[i], bf[j], acc[i][j], 0, 0, 0);
    }
#pragma unroll
    for (int i = 0; i < 4; i++)
#pragma unroll
        for (int j = 0; j < 4; j++) {
            const int col = n0 + nw + j * 16 + mf;
            if (col < NV) {
                const float bl = b_lin[col];
#pragma unroll
                for (int r = 0; r < 4; r++) {
                    const int R = m0 + mw + i * 16 + kg * 4 + r;  // = t*64 + b
                    const int b_ = R & 63, tt = R >> 6;
                    out[(size_t)b_ * ((NT - 1) * NV) + (size_t)tt * NV + col] = acc[i][j][r] + bl;
                }
            }
        }
}

extern "C" void kernel_launch(void* const* d_in, const int* in_sizes, int n_in,
                              void* d_out, int out_size, void* d_ws, size_t ws_size,
                              hipStream_t stream)
{
    const float* features = (const float*)d_in[0];
    const float* cap      = (const float*)d_in[1];
    const float* W_ih     = (const float*)d_in[2];
    const float* W_hh     = (const float*)d_in[3];
    const float* b_ih     = (const float*)d_in[4];
    const float* b_hh     = (const float*)d_in[5];
    const float* W_lin    = (const float*)d_in[6];
    const float* b_lin    = (const float*)d_in[7];
    float* out = (float*)d_out;
    unsigned char* ws = (unsigned char*)d_ws;

    hipMemsetAsync(ws + OFF_FLG, 0, (NT - 1) * sizeof(unsigned int), stream);

    hipLaunchKernelGGL(prep_kernel, dim3(7722), dim3(256), 0, stream,
                       features, cap, W_ih, W_hh, b_ih, b_hh, W_lin, ws);
    hipLaunchKernelGGL(gemm_a_kernel, dim3(16, 11), dim3(256), 0, stream, ws);
    hipLaunchKernelGGL(lstm_persistent, dim3(32), dim3(512), 0, stream, ws);
    hipLaunchKernelGGL(gemm_c_kernel, dim3(79, 10), dim3(256), 0, stream, ws, b_lin, out);
}

// Round 2
// 296.615 us; speedup vs baseline: 1.6338x; 1.1655x over previous
//
#include <hip/hip_runtime.h>
#include <hip/hip_bf16.h>

// B=64, T=21, E=H=512, V=10000. fp32 in/out.
// gates = x@W_ih^T + h@W_hh^T + (b_ih+b_hh); i,f,g,o; out = h@W_lin^T + b_lin.

#define NB 64
#define NT 21
#define NE 512
#define NH 512
#define NV 10000
#define G4 2048

typedef __attribute__((ext_vector_type(8))) short bf16x8;
typedef __attribute__((ext_vector_type(4))) float f32x4;
typedef __attribute__((ext_vector_type(4))) unsigned short u16x4;

// ---- workspace layout (bytes) ----
#define OFF_WIH_HI   0UL
#define OFF_WIH_LO   2097152UL
#define OFF_WHH_HI   4194304UL
#define OFF_WHH_LO   6291456UL
#define OFF_WLIN_HI  8388608UL     // 10112*512*2
#define OFF_XSEQ_HI  18743296UL    // 1408*512*2
#define OFF_XSEQ_LO  20185088UL
#define OFF_BIAS     21626880UL    // 2048*4
#define OFF_XIH      21635072UL    // 21*64*2048*4
#define OFF_GHH      32645120UL    // 2 x 64*512 bf16 h-hi (PRE-SWIZZLED chunk layout)
#define OFF_GHL      32776192UL    // 2 x 64*512 bf16 h-lo (PRE-SWIZZLED chunk layout)
#define OFF_C        32907264UL    // (unused; c-state lives in registers)
#define OFF_HBUF     33038336UL    // 20*64*512 bf16
#define OFF_FLG      34349056UL    // per-step barrier counters
// end 34,351,616 B

__device__ inline unsigned short f2bf(float f) {
    unsigned int u = __float_as_uint(f);
    unsigned int r = u + 0x7FFFu + ((u >> 16) & 1u);
    return (unsigned short)(r >> 16);
}
__device__ inline float bf2f(unsigned short s) {
    return __uint_as_float(((unsigned int)s) << 16);
}

__device__ __forceinline__ void gl_lds16(const unsigned short* g, unsigned short* l) {
    auto gp = (const __attribute__((address_space(1))) unsigned int*)(unsigned long long)(const void*)g;
    auto lp = (__attribute__((address_space(3))) unsigned int*)(unsigned int)(unsigned long long)(void*)l;
    __builtin_amdgcn_global_load_lds(gp, lp, 16, 0, 0);
}

// DMA that reads at the coherence point (bypass L1+L2): aux = sc0|sc1 = 1|16.
__device__ __forceinline__ void gl_lds16_sc(const unsigned short* g, unsigned short* l) {
    auto gp = (const __attribute__((address_space(1))) unsigned int*)(unsigned long long)(const void*)g;
    auto lp = (__attribute__((address_space(3))) unsigned int*)(unsigned int)(unsigned long long)(void*)l;
    __builtin_amdgcn_global_load_lds(gp, lp, 16, 0, 17);
}

// Write-through store visible at the coherence point (no wbl2 needed).
__device__ __forceinline__ void st2_sc(unsigned short* p, unsigned short v) {
    unsigned int vv = v;
    asm volatile("global_store_short %0, %1, off sc0 sc1" :: "v"(p), "v"(vv) : "memory");
}

// ---------------- prep (vectorized x4) ----------------
__global__ __launch_bounds__(256) void prep_kernel(
    const float* __restrict__ features, const float* __restrict__ cap,
    const float* __restrict__ W_ih, const float* __restrict__ W_hh,
    const float* __restrict__ b_ih, const float* __restrict__ b_hh,
    const float* __restrict__ W_lin, unsigned char* __restrict__ ws)
{
    const int idx = blockIdx.x * 256 + threadIdx.x;
    unsigned short* wih_hi = (unsigned short*)(ws + OFF_WIH_HI);
    unsigned short* wih_lo = (unsigned short*)(ws + OFF_WIH_LO);
    unsigned short* whh_hi = (unsigned short*)(ws + OFF_WHH_HI);
    unsigned short* whh_lo = (unsigned short*)(ws + OFF_WHH_LO);
    unsigned short* wlin_hi = (unsigned short*)(ws + OFF_WLIN_HI);
    unsigned short* xs_hi = (unsigned short*)(ws + OFF_XSEQ_HI);
    unsigned short* xs_lo = (unsigned short*)(ws + OFF_XSEQ_LO);
    float* bias = (float*)(ws + OFF_BIAS);

    if (idx < 262144) {
        const int i4 = idx * 4;
        float4 w = *(const float4*)(W_ih + i4);
        u16x4 hi, lo;
        hi.x = f2bf(w.x); lo.x = f2bf(w.x - bf2f(hi.x));
        hi.y = f2bf(w.y); lo.y = f2bf(w.y - bf2f(hi.y));
        hi.z = f2bf(w.z); lo.z = f2bf(w.z - bf2f(hi.z));
        hi.w = f2bf(w.w); lo.w = f2bf(w.w - bf2f(hi.w));
        *(u16x4*)(wih_hi + i4) = hi;
        *(u16x4*)(wih_lo + i4) = lo;
    } else if (idx < 524288) {
        const int i4 = (idx - 262144) * 4;
        float4 w = *(const float4*)(W_hh + i4);
        u16x4 hi, lo;
        hi.x = f2bf(w.x); lo.x = f2bf(w.x - bf2f(hi.x));
        hi.y = f2bf(w.y); lo.y = f2bf(w.y - bf2f(hi.y));
        hi.z = f2bf(w.z); lo.z = f2bf(w.z - bf2f(hi.z));
        hi.w = f2bf(w.w); lo.w = f2bf(w.w - bf2f(hi.w));
        *(u16x4*)(whh_hi + i4) = hi;
        *(u16x4*)(whh_lo + i4) = lo;
    } else if (idx < 1804288) {
        const int i4 = (idx - 524288) * 4;
        float4 w = *(const float4*)(W_lin + i4);
        u16x4 hi;
        hi.x = f2bf(w.x); hi.y = f2bf(w.y); hi.z = f2bf(w.z); hi.w = f2bf(w.w);
        *(u16x4*)(wlin_hi + i4) = hi;
    } else if (idx < 1976320) {
        const int i4 = (idx - 1804288) * 4;
        const int e = i4 & 511;
        const int b = (i4 >> 9) & 63;
        const int t = i4 >> 15;
        float4 x = (t == 0) ? *(const float4*)(features + b * NE + e)
                            : *(const float4*)(cap + b * (NT * NE) + (t - 1) * NE + e);
        u16x4 hi, lo;
        hi.x = f2bf(x.x); lo.x = f2bf(x.x - bf2f(hi.x));
        hi.y = f2bf(x.y); lo.y = f2bf(x.y - bf2f(hi.y));
        hi.z = f2bf(x.z); lo.z = f2bf(x.z - bf2f(hi.z));
        hi.w = f2bf(x.w); lo.w = f2bf(x.w - bf2f(hi.w));
        *(u16x4*)(xs_hi + i4) = hi;
        *(u16x4*)(xs_lo + i4) = lo;
    } else if (idx < 1976832) {
        const int j = (idx - 1976320) * 4;
        float4 a = *(const float4*)(b_ih + j);
        float4 b = *(const float4*)(b_hh + j);
        *(float4*)(bias + j) = make_float4(a.x + b.x, a.y + b.y, a.z + b.z, a.w + b.w);
    }
}

// ---------------- phase A: Xih = Xseq @ W_ih^T + bias, hi/lo 3-pass, tiled ----------------
__global__ __launch_bounds__(256) void gemm_a_kernel(unsigned char* __restrict__ ws)
{
    __shared__ unsigned short Ah[2][4096], Al[2][4096], Bh[2][4096], Bl[2][4096];
    const int tid = threadIdx.x;
    const int lane = tid & 63, wv = tid >> 6;
    const int mf = lane & 15, kg = lane >> 4;
    const int mw = (wv >> 1) * 64, nw = (wv & 1) * 64;
    const int m0 = blockIdx.y * 128, n0 = blockIdx.x * 128;

    const unsigned short* __restrict__ xh = (const unsigned short*)(ws + OFF_XSEQ_HI);
    const unsigned short* __restrict__ xl = (const unsigned short*)(ws + OFF_XSEQ_LO);
    const unsigned short* __restrict__ wh = (const unsigned short*)(ws + OFF_WIH_HI);
    const unsigned short* __restrict__ wl = (const unsigned short*)(ws + OFF_WIH_LO);
    const float* __restrict__ bias = (const float*)(ws + OFF_BIAS);
    float* __restrict__ xih = (float*)(ws + OFF_XIH);

    f32x4 acc[4][4];
#pragma unroll
    for (int i = 0; i < 4; i++)
#pragma unroll
        for (int j = 0; j < 4; j++) acc[i][j] = (f32x4){0.f, 0.f, 0.f, 0.f};

    auto stage = [&](int buf, int k0) {
#pragma unroll
        for (int h = 0; h < 2; ++h) {
            int s = h * 256 + tid;
            int r = s >> 2, ks = (s & 3) * 8;
            gl_lds16(xh + (size_t)(m0 + r) * 512 + k0 + ks, &Ah[buf][s * 8]);
            gl_lds16(xl + (size_t)(m0 + r) * 512 + k0 + ks, &Al[buf][s * 8]);
            gl_lds16(wh + (size_t)(n0 + r) * 512 + k0 + ks, &Bh[buf][s * 8]);
            gl_lds16(wl + (size_t)(n0 + r) * 512 + k0 + ks, &Bl[buf][s * 8]);
        }
    };

    stage(0, 0);
    for (int kt = 0; kt < 16; ++kt) {
        __syncthreads();
        const int cur = kt & 1;
        if (kt < 15) stage(cur ^ 1, (kt + 1) * 32);
        bf16x8 ah[4], al[4], bh[4], bl[4];
#pragma unroll
        for (int i = 0; i < 4; i++) {
            ah[i] = *(const bf16x8*)&Ah[cur][(mw + i * 16 + mf) * 32 + kg * 8];
            al[i] = *(const bf16x8*)&Al[cur][(mw + i * 16 + mf) * 32 + kg * 8];
            bh[i] = *(const bf16x8*)&Bh[cur][(nw + i * 16 + mf) * 32 + kg * 8];
            bl[i] = *(const bf16x8*)&Bl[cur][(nw + i * 16 + mf) * 32 + kg * 8];
        }
#pragma unroll
        for (int i = 0; i < 4; i++)
#pragma unroll
            for (int j = 0; j < 4; j++) {
                acc[i][j] = __builtin_amdgcn_mfma_f32_16x16x32_bf16(ah[i], bh[j], acc[i][j], 0, 0, 0);
                acc[i][j] = __builtin_amdgcn_mfma_f32_16x16x32_bf16(ah[i], bl[j], acc[i][j], 0, 0, 0);
                acc[i][j] = __builtin_amdgcn_mfma_f32_16x16x32_bf16(al[i], bh[j], acc[i][j], 0, 0, 0);
            }
    }
#pragma unroll
    for (int i = 0; i < 4; i++)
#pragma unroll
        for (int j = 0; j < 4; j++) {
            const int col = n0 + nw + j * 16 + mf;
            const float bb = bias[col];
#pragma unroll
            for (int r = 0; r < 4; r++) {
                const int R = m0 + mw + i * 16 + kg * 4 + r;
                if (R < NT * NB) xih[(size_t)R * G4 + col] = acc[i][j][r] + bb;
            }
        }
}

// ---------------- phase B: persistent LSTM ----------------
// 32 blocks x 512 thr. 8 waves = 4 gate quadrants x 2 row-halves; each wave
// does the FULL K=512 with W_hh hi+lo fragments register-resident, so
// accumulators are complete gate sums (no K-split reduction).
// Cross-step h: hi/lo stored with sc0|sc1 (write-through to coherence point)
// and DMA'd back with sc0|sc1 (read at coherence point) -> NO buffer_wbl2 /
// buffer_inv fences at all; read-only data (W_hh, xih) stays L2-warm across
// all steps. Counted vmcnt(8)+s_barrier releases the hi half early so hi-pass
// MFMAs overlap the lo-half DMA stream. c-state in registers; next-step xih
// prefetched into registers before the inter-block barrier.
__global__ __launch_bounds__(512, 2) void lstm_persistent(unsigned char* __restrict__ ws)
{
    __shared__ unsigned short Hhi[64 * 512];   // 64 KB h-hi image
    __shared__ unsigned short Hlo[64 * 512];   // 64 KB h-lo image
    __shared__ float glf[4096];                // 16 KB gate values
    const int tid = threadIdx.x;
    const int lane = tid & 63, wv = tid >> 6;
    const int mf = lane & 15, kg = lane >> 4;
    const int q = wv & 3;        // gate quadrant
    const int mh = wv >> 2;      // row half (rows mh*32 .. mh*32+31)
    const int bc = blockIdx.x;

    unsigned short* __restrict__ ghh = (unsigned short*)(ws + OFF_GHH);
    unsigned short* __restrict__ ghl = (unsigned short*)(ws + OFF_GHL);
    const unsigned short* __restrict__ whh_hi = (const unsigned short*)(ws + OFF_WHH_HI);
    const unsigned short* __restrict__ whh_lo = (const unsigned short*)(ws + OFF_WHH_LO);
    const float* __restrict__ xih_base = (const float*)(ws + OFF_XIH);
    unsigned short* __restrict__ hbuf = (unsigned short*)(ws + OFF_HBUF);
    unsigned int* __restrict__ ctr = (unsigned int*)(ws + OFF_FLG);

    // ---- preload W_hh hi+lo fragments, full K: cols q*512+bc*16+mf ----
    bf16x8 bh[16], blo[16];
#pragma unroll
    for (int j = 0; j < 16; ++j) {
        const size_t off = (size_t)(q * 512 + bc * 16 + mf) * 512 + j * 32 + kg * 8;
        bh[j] = *(const bf16x8*)(whh_hi + off);
        blo[j] = *(const bf16x8*)(whh_lo + off);
    }

    // ---- per-thread cell mapping (2 cells/thread) + register state ----
    const int row0 = tid >> 4;          // cc=0 row in [0,32)
    const int row1 = row0 + 32;         // cc=1 row in [32,64)
    const int ci = tid & 15;
    const int c = bc * 16 + ci;
    const int jc = c >> 3;
    float creg[2] = {0.f, 0.f};

    float xp[8];
    auto load_xp = [&](int tt) {
        const float* __restrict__ xq = xih_base + (size_t)tt * NB * G4;
#pragma unroll
        for (int g = 0; g < 4; ++g) {
            xp[g]     = xq[row0 * G4 + g * 512 + c];
            xp[4 + g] = xq[row1 * G4 + g * 512 + c];
        }
    };
    load_xp(0);

    for (int t = 0; t < NT; ++t) {
        f32x4 acc[2];
        acc[0] = (f32x4){0.f, 0.f, 0.f, 0.f};
        acc[1] = (f32x4){0.f, 0.f, 0.f, 0.f};

        if (t > 0) {
            const int rd = (t + 1) & 1;
            const unsigned short* __restrict__ ghh_r = ghh + rd * (NB * NH);
            const unsigned short* __restrict__ ghl_r = ghl + rd * (NB * NH);
            // ---- bulk DMA: 8 hi insts then 8 lo insts per thread (128 KB),
            //      sc0|sc1 -> reads the coherence point directly ----
#pragma unroll
            for (int i = 0; i < 8; ++i) {
                const int s = i * 512 + tid;
                gl_lds16_sc(ghh_r + s * 8, &Hhi[s * 8]);
            }
#pragma unroll
            for (int i = 0; i < 8; ++i) {
                const int s = i * 512 + tid;
                gl_lds16_sc(ghl_r + s * 8, &Hlo[s * 8]);
            }
            // hi half done (my 8 oldest of 16); barrier -> all waves' hi done
            asm volatile("s_waitcnt vmcnt(8)" ::: "memory");
            __builtin_amdgcn_s_barrier();
            // ---- hi passes: a_hi x (B_hi + B_lo), lo DMA still streaming ----
#pragma unroll
            for (int kt = 0; kt < 16; ++kt) {
                const int j = kt * 4 + kg;
#pragma unroll
                for (int m = 0; m < 2; ++m) {
                    const int row = mh * 32 + m * 16 + mf;
                    bf16x8 a_hi = *(const bf16x8*)&Hhi[(row * 64 + (j ^ (row & 7))) * 8];
                    acc[m] = __builtin_amdgcn_mfma_f32_16x16x32_bf16(a_hi, bh[kt], acc[m], 0, 0, 0);
                    acc[m] = __builtin_amdgcn_mfma_f32_16x16x32_bf16(a_hi, blo[kt], acc[m], 0, 0, 0);
                }
            }
            // lo half done everywhere
            asm volatile("s_waitcnt vmcnt(0)" ::: "memory");
            __builtin_amdgcn_s_barrier();
            // ---- lo pass: a_lo x B_hi ----
#pragma unroll
            for (int kt = 0; kt < 16; ++kt) {
                const int j = kt * 4 + kg;
#pragma unroll
                for (int m = 0; m < 2; ++m) {
                    const int row = mh * 32 + m * 16 + mf;
                    bf16x8 a_lo = *(const bf16x8*)&Hlo[(row * 64 + (j ^ (row & 7))) * 8];
                    acc[m] = __builtin_amdgcn_mfma_f32_16x16x32_bf16(a_lo, bh[kt], acc[m], 0, 0, 0);
                }
            }
        }

        // ---- full gate sums straight to LDS ----
#pragma unroll
        for (int m = 0; m < 2; ++m) {
            const int row = mh * 32 + m * 16 + kg * 4;
#pragma unroll
            for (int r = 0; r < 4; ++r)
                glf[(q * 64 + row + r) * 16 + mf] = acc[m][r];
        }
        __syncthreads();

        // ---- LSTM cell: 1024 cells over 512 threads, c in registers ----
        unsigned short* __restrict__ ghh_w = ghh + (t & 1) * (NB * NH);
        unsigned short* __restrict__ ghl_w = ghl + (t & 1) * (NB * NH);
#pragma unroll
        for (int cc = 0; cc < 2; ++cc) {
            const int row = cc ? row1 : row0;
            const float gi = glf[(0 * 64 + row) * 16 + ci] + xp[cc * 4 + 0];
            const float gf = glf[(1 * 64 + row) * 16 + ci] + xp[cc * 4 + 1];
            const float gg = glf[(2 * 64 + row) * 16 + ci] + xp[cc * 4 + 2];
            const float go = glf[(3 * 64 + row) * 16 + ci] + xp[cc * 4 + 3];
            const float i_ = 1.f / (1.f + __expf(-gi));
            const float f_ = 1.f / (1.f + __expf(-gf));
            const float g_ = tanhf(gg);
            const float o_ = 1.f / (1.f + __expf(-go));
            const float c_new = f_ * creg[cc] + i_ * g_;
            creg[cc] = c_new;
            const float h_new = o_ * tanhf(c_new);
            const unsigned short hi = f2bf(h_new);
            const unsigned short lo = f2bf(h_new - bf2f(hi));
            // hi AND lo: swizzled chunk layout (chunk j' = j ^ (row&7)),
            // write-through to coherence point (sc0 sc1)
            const int sw = row * 512 + ((jc ^ (row & 7)) << 3) + (c & 7);
            st2_sc(&ghh_w[sw], hi);
            st2_sc(&ghl_w[sw], lo);
            if (t >= 1)
                __builtin_nontemporal_store(hi, &hbuf[(t - 1) * (NB * NH) + row * NH + c]);
        }

        if (t < NT - 1) {
            load_xp(t + 1);    // prefetch next step's gate inputs (read-only data)
            asm volatile("s_waitcnt vmcnt(0)" ::: "memory");  // h-stores at coherence point
            __syncthreads();   // ... for ALL threads
            if (tid == 0) {
                __hip_atomic_fetch_add(&ctr[t], 1u, __ATOMIC_RELAXED, __HIP_MEMORY_SCOPE_AGENT);
                while (__hip_atomic_load(&ctr[t], __ATOMIC_RELAXED, __HIP_MEMORY_SCOPE_AGENT) < 32u)
                    __builtin_amdgcn_s_sleep(1);
            }
            __syncthreads();
            // no acquire fence: the only cross-step-shared reads (h DMA) carry
            // sc0|sc1 themselves and read the coherence point.
        }
    }
}

// ---------------- phase C: Out = Hbuf[1280x512] @ W_lin^T + b_lin, tiled ----------------
__global__ __launch_bounds__(256) void gemm_c_kernel(
    unsigned char* __restrict__ ws, const float* __restrict__ b_lin, float* __restrict__ out)
{
    __shared__ unsigned short As[2][4096], Bs[2][4096];
    const int tid = threadIdx.x;
    const int lane = tid & 63, wv = tid >> 6;
    const int mf = lane & 15, kg = lane >> 4;
    const int mw = (wv >> 1) * 64, nw = (wv & 1) * 64;
    const int m0 = blockIdx.y * 128, n0 = blockIdx.x * 128;

    const unsigned short* __restrict__ hb = (const unsigned short*)(ws + OFF_HBUF);
    const unsigned short* __restrict__ wlin = (const unsigned short*)(ws + OFF_WLIN_HI);

    f32x4 acc[4][4];
#pragma unroll
    for (int i = 0; i < 4; i++)
#pragma unroll
        for (int j = 0; j < 4; j++) acc[i][j] = (f32x4){0.f, 0.f, 0.f, 0.f};

    auto stage = [&](int buf, int k0) {
#pragma unroll
        for (int h = 0; h < 2; ++h) {
            int s = h * 256 + tid;
            int r = s >> 2, ks = (s & 3) * 8;
            gl_lds16(hb + (size_t)(m0 + r) * 512 + k0 + ks, &As[buf][s * 8]);
            gl_lds16(wlin + (size_t)(n0 + r) * 512 + k0 + ks, &Bs[buf][s * 8]);
        }
    };

    stage(0, 0);
    for (int kt = 0; kt < 16; ++kt) {
        __syncthreads();
        const int cur = kt & 1;
        if (kt < 15) stage(cur ^ 1, (kt + 1) * 32);
        bf16x8 af[4], bf[4];
#pragma unroll
        for (int i = 0; i < 4; i++) {
            af[i] = *(const bf16x8*)&As[cur][(mw + i * 16 + mf) * 32 + kg * 8];
            bf[i] = *(const bf16x8*)&Bs[cur][(nw + i * 16 + mf) * 32 + kg * 8];
        }
#pragma unroll
        for (int i = 0; i < 4; i++)
#pragma unroll
            for (int j = 0; j < 4; j++)
                acc[i][j] = __builtin_amdgcn_mfma_f32_16x16x32_bf16(af[i], bf[j], acc[i][j], 0, 0, 0);
    }
#pragma unroll
    for (int i = 0; i < 4; i++)
#pragma unroll
        for (int j = 0; j < 4; j++) {
            const int col = n0 + nw + j * 16 + mf;
            if (col < NV) {
                const float bl = b_lin[col];
#pragma unroll
                for (int r = 0; r < 4; r++) {
                    const int R = m0 + mw + i * 16 + kg * 4 + r;  // = t*64 + b
                    const int b_ = R & 63, tt = R >> 6;
                    out[(size_t)b_ * ((NT - 1) * NV) + (size_t)tt * NV + col] = acc[i][j][r] + bl;
                }
            }
        }
}

extern "C" void kernel_launch(void* const* d_in, const int* in_sizes, int n_in,
                              void* d_out, int out_size, void* d_ws, size_t ws_size,
                              hipStream_t stream)
{
    const float* features = (const float*)d_in[0];
    const float* cap      = (const float*)d_in[1];
    const float* W_ih     = (const float*)d_in[2];
    const float* W_hh     = (const float*)d_in[3];
    const float* b_ih     = (const float*)d_in[4];
    const float* b_hh     = (const float*)d_in[5];
    const float* W_lin    = (const float*)d_in[6];
    const float* b_lin    = (const float*)d_in[7];
    float* out = (float*)d_out;
    unsigned char* ws = (unsigned char*)d_ws;

    hipMemsetAsync(ws + OFF_FLG, 0, (NT - 1) * sizeof(unsigned int), stream);

    hipLaunchKernelGGL(prep_kernel, dim3(7722), dim3(256), 0, stream,
                       features, cap, W_ih, W_hh, b_ih, b_hh, W_lin, ws);
    hipLaunchKernelGGL(gemm_a_kernel, dim3(16, 11), dim3(256), 0, stream, ws);
    hipLaunchKernelGGL(lstm_persistent, dim3(32), dim3(512), 0, stream, ws);
    hipLaunchKernelGGL(gemm_c_kernel, dim3(79, 10), dim3(256), 0, stream, ws, b_lin, out);
}

// Round 3
// 257.831 us; speedup vs baseline: 1.8796x; 1.1504x over previous
//
#include <hip/hip_runtime.h>
#include <hip/hip_bf16.h>

// B=64, T=21, E=H=512, V=10000. fp32 in/out.
// gates = x@W_ih^T + h@W_hh^T + (b_ih+b_hh); i,f,g,o; out = h@W_lin^T + b_lin.

#define NB 64
#define NT 21
#define NE 512
#define NH 512
#define NV 10000
#define G4 2048
#define FLGD 16   // dwords per flag slot (64B line padding)

typedef __attribute__((ext_vector_type(8))) short bf16x8;
typedef __attribute__((ext_vector_type(4))) float f32x4;
typedef __attribute__((ext_vector_type(4))) unsigned short u16x4;

// ---- workspace layout (bytes) ----
#define OFF_WIH_HI   0UL
#define OFF_WIH_LO   2097152UL
#define OFF_WHH_HI   4194304UL
#define OFF_WHH_LO   6291456UL
#define OFF_WLIN_HI  8388608UL     // 10112*512*2
#define OFF_XSEQ_HI  18743296UL    // 1408*512*2
#define OFF_XSEQ_LO  20185088UL
#define OFF_BIAS     21626880UL    // 2048*4
#define OFF_XIH      21635072UL    // 21*64*2048*4
#define OFF_GHH      32645120UL    // 2 x 64*512 bf16 h-hi (PRE-SWIZZLED chunk layout)
#define OFF_GHL      32776192UL    // 2 x 64*512 bf16 h-lo (PRE-SWIZZLED chunk layout)
#define OFF_C        32907264UL    // ready flags: 21 steps x 32 blocks x 64B = 43008 B
#define OFF_HBUF     33038336UL    // 20*64*512 bf16 (sc-visible mid-kernel)
#define OFF_FLG      34349056UL    // (unused legacy)
// end 34,351,616 B

__device__ inline unsigned short f2bf(float f) {
    unsigned int u = __float_as_uint(f);
    unsigned int r = u + 0x7FFFu + ((u >> 16) & 1u);
    return (unsigned short)(r >> 16);
}
__device__ inline float bf2f(unsigned short s) {
    return __uint_as_float(((unsigned int)s) << 16);
}

__device__ __forceinline__ void gl_lds16(const unsigned short* g, unsigned short* l) {
    auto gp = (const __attribute__((address_space(1))) unsigned int*)(unsigned long long)(const void*)g;
    auto lp = (__attribute__((address_space(3))) unsigned int*)(unsigned int)(unsigned long long)(void*)l;
    __builtin_amdgcn_global_load_lds(gp, lp, 16, 0, 0);
}

// DMA that reads at the coherence point (bypass L1+L2): aux = sc0|sc1 = 1|16.
__device__ __forceinline__ void gl_lds16_sc(const unsigned short* g, unsigned short* l) {
    auto gp = (const __attribute__((address_space(1))) unsigned int*)(unsigned long long)(const void*)g;
    auto lp = (__attribute__((address_space(3))) unsigned int*)(unsigned int)(unsigned long long)(void*)l;
    __builtin_amdgcn_global_load_lds(gp, lp, 16, 0, 17);
}

// Write-through dword store visible at the coherence point.
__device__ __forceinline__ void st4_sc(unsigned int* p, unsigned int v) {
    asm volatile("global_store_dword %0, %1, off sc0 sc1" :: "v"(p), "v"(v) : "memory");
}

// ---------------- prep (vectorized x4) ----------------
__global__ __launch_bounds__(256) void prep_kernel(
    const float* __restrict__ features, const float* __restrict__ cap,
    const float* __restrict__ W_ih, const float* __restrict__ W_hh,
    const float* __restrict__ b_ih, const float* __restrict__ b_hh,
    const float* __restrict__ W_lin, unsigned char* __restrict__ ws)
{
    const int idx = blockIdx.x * 256 + threadIdx.x;
    unsigned short* wih_hi = (unsigned short*)(ws + OFF_WIH_HI);
    unsigned short* wih_lo = (unsigned short*)(ws + OFF_WIH_LO);
    unsigned short* whh_hi = (unsigned short*)(ws + OFF_WHH_HI);
    unsigned short* whh_lo = (unsigned short*)(ws + OFF_WHH_LO);
    unsigned short* wlin_hi = (unsigned short*)(ws + OFF_WLIN_HI);
    unsigned short* xs_hi = (unsigned short*)(ws + OFF_XSEQ_HI);
    unsigned short* xs_lo = (unsigned short*)(ws + OFF_XSEQ_LO);
    float* bias = (float*)(ws + OFF_BIAS);

    if (idx < 262144) {
        const int i4 = idx * 4;
        float4 w = *(const float4*)(W_ih + i4);
        u16x4 hi, lo;
        hi.x = f2bf(w.x); lo.x = f2bf(w.x - bf2f(hi.x));
        hi.y = f2bf(w.y); lo.y = f2bf(w.y - bf2f(hi.y));
        hi.z = f2bf(w.z); lo.z = f2bf(w.z - bf2f(hi.z));
        hi.w = f2bf(w.w); lo.w = f2bf(w.w - bf2f(hi.w));
        *(u16x4*)(wih_hi + i4) = hi;
        *(u16x4*)(wih_lo + i4) = lo;
    } else if (idx < 524288) {
        const int i4 = (idx - 262144) * 4;
        float4 w = *(const float4*)(W_hh + i4);
        u16x4 hi, lo;
        hi.x = f2bf(w.x); lo.x = f2bf(w.x - bf2f(hi.x));
        hi.y = f2bf(w.y); lo.y = f2bf(w.y - bf2f(hi.y));
        hi.z = f2bf(w.z); lo.z = f2bf(w.z - bf2f(hi.z));
        hi.w = f2bf(w.w); lo.w = f2bf(w.w - bf2f(hi.w));
        *(u16x4*)(whh_hi + i4) = hi;
        *(u16x4*)(whh_lo + i4) = lo;
    } else if (idx < 1804288) {
        const int i4 = (idx - 524288) * 4;
        float4 w = *(const float4*)(W_lin + i4);
        u16x4 hi;
        hi.x = f2bf(w.x); hi.y = f2bf(w.y); hi.z = f2bf(w.z); hi.w = f2bf(w.w);
        *(u16x4*)(wlin_hi + i4) = hi;
    } else if (idx < 1976320) {
        const int i4 = (idx - 1804288) * 4;
        const int e = i4 & 511;
        const int b = (i4 >> 9) & 63;
        const int t = i4 >> 15;
        float4 x = (t == 0) ? *(const float4*)(features + b * NE + e)
                            : *(const float4*)(cap + b * (NT * NE) + (t - 1) * NE + e);
        u16x4 hi, lo;
        hi.x = f2bf(x.x); lo.x = f2bf(x.x - bf2f(hi.x));
        hi.y = f2bf(x.y); lo.y = f2bf(x.y - bf2f(hi.y));
        hi.z = f2bf(x.z); lo.z = f2bf(x.z - bf2f(hi.z));
        hi.w = f2bf(x.w); lo.w = f2bf(x.w - bf2f(hi.w));
        *(u16x4*)(xs_hi + i4) = hi;
        *(u16x4*)(xs_lo + i4) = lo;
    } else if (idx < 1976832) {
        const int j = (idx - 1976320) * 4;
        float4 a = *(const float4*)(b_ih + j);
        float4 b = *(const float4*)(b_hh + j);
        *(float4*)(bias + j) = make_float4(a.x + b.x, a.y + b.y, a.z + b.z, a.w + b.w);
    }
}

// ---------------- phase A: Xih = Xseq @ W_ih^T + bias, hi/lo 3-pass, tiled ----------------
__global__ __launch_bounds__(256) void gemm_a_kernel(unsigned char* __restrict__ ws)
{
    __shared__ unsigned short Ah[2][4096], Al[2][4096], Bh[2][4096], Bl[2][4096];
    const int tid = threadIdx.x;
    const int lane = tid & 63, wv = tid >> 6;
    const int mf = lane & 15, kg = lane >> 4;
    const int mw = (wv >> 1) * 64, nw = (wv & 1) * 64;
    const int m0 = blockIdx.y * 128, n0 = blockIdx.x * 128;

    const unsigned short* __restrict__ xh = (const unsigned short*)(ws + OFF_XSEQ_HI);
    const unsigned short* __restrict__ xl = (const unsigned short*)(ws + OFF_XSEQ_LO);
    const unsigned short* __restrict__ wh = (const unsigned short*)(ws + OFF_WIH_HI);
    const unsigned short* __restrict__ wl = (const unsigned short*)(ws + OFF_WIH_LO);
    const float* __restrict__ bias = (const float*)(ws + OFF_BIAS);
    float* __restrict__ xih = (float*)(ws + OFF_XIH);

    f32x4 acc[4][4];
#pragma unroll
    for (int i = 0; i < 4; i++)
#pragma unroll
        for (int j = 0; j < 4; j++) acc[i][j] = (f32x4){0.f, 0.f, 0.f, 0.f};

    auto stage = [&](int buf, int k0) {
#pragma unroll
        for (int h = 0; h < 2; ++h) {
            int s = h * 256 + tid;
            int r = s >> 2, ks = (s & 3) * 8;
            gl_lds16(xh + (size_t)(m0 + r) * 512 + k0 + ks, &Ah[buf][s * 8]);
            gl_lds16(xl + (size_t)(m0 + r) * 512 + k0 + ks, &Al[buf][s * 8]);
            gl_lds16(wh + (size_t)(n0 + r) * 512 + k0 + ks, &Bh[buf][s * 8]);
            gl_lds16(wl + (size_t)(n0 + r) * 512 + k0 + ks, &Bl[buf][s * 8]);
        }
    };

    stage(0, 0);
    for (int kt = 0; kt < 16; ++kt) {
        __syncthreads();
        const int cur = kt & 1;
        if (kt < 15) stage(cur ^ 1, (kt + 1) * 32);
        bf16x8 ah[4], al[4], bh[4], bl[4];
#pragma unroll
        for (int i = 0; i < 4; i++) {
            ah[i] = *(const bf16x8*)&Ah[cur][(mw + i * 16 + mf) * 32 + kg * 8];
            al[i] = *(const bf16x8*)&Al[cur][(mw + i * 16 + mf) * 32 + kg * 8];
            bh[i] = *(const bf16x8*)&Bh[cur][(nw + i * 16 + mf) * 32 + kg * 8];
            bl[i] = *(const bf16x8*)&Bl[cur][(nw + i * 16 + mf) * 32 + kg * 8];
        }
#pragma unroll
        for (int i = 0; i < 4; i++)
#pragma unroll
            for (int j = 0; j < 4; j++) {
                acc[i][j] = __builtin_amdgcn_mfma_f32_16x16x32_bf16(ah[i], bh[j], acc[i][j], 0, 0, 0);
                acc[i][j] = __builtin_amdgcn_mfma_f32_16x16x32_bf16(ah[i], bl[j], acc[i][j], 0, 0, 0);
                acc[i][j] = __builtin_amdgcn_mfma_f32_16x16x32_bf16(al[i], bh[j], acc[i][j], 0, 0, 0);
            }
    }
#pragma unroll
    for (int i = 0; i < 4; i++)
#pragma unroll
        for (int j = 0; j < 4; j++) {
            const int col = n0 + nw + j * 16 + mf;
            const float bb = bias[col];
#pragma unroll
            for (int r = 0; r < 4; r++) {
                const int R = m0 + mw + i * 16 + kg * 4 + r;
                if (R < NT * NB) xih[(size_t)R * G4 + col] = acc[i][j][r] + bb;
            }
        }
}

// ---------------- fused persistent: LSTM (blocks 0..31) + streamed phase-C (32..255) ----
// Grid = 256 blocks x 512 thr, 147456 B LDS -> exactly 1 block/CU -> all blocks
// co-resident (no dispatch-order deadlock window).
// LSTM blocks: as round 2, plus (a) padded per-block ready-flags instead of the
// contended counter barrier (one sc0sc1 store; relaxed agent-load polling),
// (b) cell remapped to 2 adjacent cols/thread -> h-hi/h-lo/hbuf are single
// packed dword sc-stores, glf/xih reads are float2, (c) hbuf is sc-visible so
// consumer blocks can stream phase-C DURING the recurrence.
// Phase-C blocks: fixed 128-col tile jt=g%79 (B stays L2-resident); 2-3 blocks
// share a column and split the 20 t-slabs; poll flag[t+1] (== h(t+1) stored ==
// hbuf slab t complete), then compute the 64x128 out tile (identical MFMA
// accumulation order as the old gemm_c -> bit-identical output).
__global__ __launch_bounds__(512, 2) void fused_persistent(
    unsigned char* __restrict__ ws, const float* __restrict__ b_lin, float* __restrict__ out)
{
    __shared__ unsigned short Hhi[64 * 512];   // lstm: h-hi image | gemm: As/Bs tiles
    __shared__ unsigned short Hlo[64 * 512];   // lstm: h-lo image
    __shared__ float glf[4096];                // lstm: gate values
    const int tid = threadIdx.x;
    const int lane = tid & 63, wv = tid >> 6;
    const int mf = lane & 15, kg = lane >> 4;

    unsigned int* __restrict__ flg = (unsigned int*)(ws + OFF_C);
    unsigned short* __restrict__ hbuf = (unsigned short*)(ws + OFF_HBUF);
    const unsigned short* __restrict__ wlin = (const unsigned short*)(ws + OFF_WLIN_HI);

    if (blockIdx.x < 32) {
        // ================= LSTM recurrence =================
        const int bc = blockIdx.x;
        const int q = wv & 3;        // gate quadrant
        const int mh = wv >> 2;      // row half

        unsigned short* __restrict__ ghh = (unsigned short*)(ws + OFF_GHH);
        unsigned short* __restrict__ ghl = (unsigned short*)(ws + OFF_GHL);
        const unsigned short* __restrict__ whh_hi = (const unsigned short*)(ws + OFF_WHH_HI);
        const unsigned short* __restrict__ whh_lo = (const unsigned short*)(ws + OFF_WHH_LO);
        const float* __restrict__ xih_base = (const float*)(ws + OFF_XIH);

        // ---- preload W_hh hi+lo fragments, full K: cols q*512+bc*16+mf ----
        bf16x8 bh[16], blo[16];
#pragma unroll
        for (int j = 0; j < 16; ++j) {
            const size_t off = (size_t)(q * 512 + bc * 16 + mf) * 512 + j * 32 + kg * 8;
            bh[j] = *(const bf16x8*)(whh_hi + off);
            blo[j] = *(const bf16x8*)(whh_lo + off);
        }

        // ---- per-thread cell mapping: 2 ADJACENT cols of one row ----
        const int crow = tid >> 3;           // batch row 0..63
        const int cp = tid & 7;              // col-pair 0..7
        const int c0 = bc * 16 + cp * 2;     // first hidden col
        const int jc0 = c0 >> 3;             // chunk index (both cols same chunk)
        float creg0 = 0.f, creg1 = 0.f;

        float2 xp[4];
        auto load_xp = [&](int tt) {
            const float* __restrict__ xq = xih_base + (size_t)tt * NB * G4;
#pragma unroll
            for (int g2 = 0; g2 < 4; ++g2)
                xp[g2] = *(const float2*)&xq[crow * G4 + g2 * 512 + c0];
        };
        load_xp(0);

        for (int t = 0; t < NT; ++t) {
            f32x4 acc[2];
            acc[0] = (f32x4){0.f, 0.f, 0.f, 0.f};
            acc[1] = (f32x4){0.f, 0.f, 0.f, 0.f};

            if (t > 0) {
                const int rd = (t + 1) & 1;
                const unsigned short* __restrict__ ghh_r = ghh + rd * (NB * NH);
                const unsigned short* __restrict__ ghl_r = ghl + rd * (NB * NH);
                // ---- bulk DMA: 8 hi + 8 lo insts/thread (128 KB), sc-reads ----
#pragma unroll
                for (int i = 0; i < 8; ++i) {
                    const int s = i * 512 + tid;
                    gl_lds16_sc(ghh_r + s * 8, &Hhi[s * 8]);
                }
#pragma unroll
                for (int i = 0; i < 8; ++i) {
                    const int s = i * 512 + tid;
                    gl_lds16_sc(ghl_r + s * 8, &Hlo[s * 8]);
                }
                // hi half done (vmcnt was 0 at loop entry: syncthreads drains)
                asm volatile("s_waitcnt vmcnt(8)" ::: "memory");
                __builtin_amdgcn_s_barrier();
                // ---- hi passes: a_hi x (B_hi + B_lo), lo DMA still streaming ----
#pragma unroll
                for (int kt = 0; kt < 16; ++kt) {
                    const int j = kt * 4 + kg;
#pragma unroll
                    for (int m = 0; m < 2; ++m) {
                        const int row = mh * 32 + m * 16 + mf;
                        bf16x8 a_hi = *(const bf16x8*)&Hhi[(row * 64 + (j ^ (row & 7))) * 8];
                        acc[m] = __builtin_amdgcn_mfma_f32_16x16x32_bf16(a_hi, bh[kt], acc[m], 0, 0, 0);
                        acc[m] = __builtin_amdgcn_mfma_f32_16x16x32_bf16(a_hi, blo[kt], acc[m], 0, 0, 0);
                    }
                }
                asm volatile("s_waitcnt vmcnt(0)" ::: "memory");
                __builtin_amdgcn_s_barrier();
                // ---- lo pass: a_lo x B_hi ----
#pragma unroll
                for (int kt = 0; kt < 16; ++kt) {
                    const int j = kt * 4 + kg;
#pragma unroll
                    for (int m = 0; m < 2; ++m) {
                        const int row = mh * 32 + m * 16 + mf;
                        bf16x8 a_lo = *(const bf16x8*)&Hlo[(row * 64 + (j ^ (row & 7))) * 8];
                        acc[m] = __builtin_amdgcn_mfma_f32_16x16x32_bf16(a_lo, bh[kt], acc[m], 0, 0, 0);
                    }
                }
            }

            // ---- full gate sums straight to LDS ----
#pragma unroll
            for (int m = 0; m < 2; ++m) {
                const int row = mh * 32 + m * 16 + kg * 4;
#pragma unroll
                for (int r = 0; r < 4; ++r)
                    glf[(q * 64 + row + r) * 16 + mf] = acc[m][r];
            }
            __syncthreads();

            // ---- LSTM cell: 1024 cells, 2 adjacent cols/thread, packed stores ----
            {
                unsigned short* __restrict__ ghh_w = ghh + (t & 1) * (NB * NH);
                unsigned short* __restrict__ ghl_w = ghl + (t & 1) * (NB * NH);
                const float2 g0 = *(const float2*)&glf[(0 * 64 + crow) * 16 + cp * 2];
                const float2 g1 = *(const float2*)&glf[(1 * 64 + crow) * 16 + cp * 2];
                const float2 g2 = *(const float2*)&glf[(2 * 64 + crow) * 16 + cp * 2];
                const float2 g3 = *(const float2*)&glf[(3 * 64 + crow) * 16 + cp * 2];
                const float gi0 = g0.x + xp[0].x, gi1 = g0.y + xp[0].y;
                const float gf0 = g1.x + xp[1].x, gf1 = g1.y + xp[1].y;
                const float gg0 = g2.x + xp[2].x, gg1 = g2.y + xp[2].y;
                const float go0 = g3.x + xp[3].x, go1 = g3.y + xp[3].y;
                const float i0 = 1.f / (1.f + __expf(-gi0)), i1 = 1.f / (1.f + __expf(-gi1));
                const float f0 = 1.f / (1.f + __expf(-gf0)), f1 = 1.f / (1.f + __expf(-gf1));
                const float ga0 = tanhf(gg0),                ga1 = tanhf(gg1);
                const float o0 = 1.f / (1.f + __expf(-go0)), o1 = 1.f / (1.f + __expf(-go1));
                const float cn0 = f0 * creg0 + i0 * ga0;
                const float cn1 = f1 * creg1 + i1 * ga1;
                creg0 = cn0; creg1 = cn1;
                const float h0 = o0 * tanhf(cn0);
                const float h1 = o1 * tanhf(cn1);
                const unsigned short hi0 = f2bf(h0), hi1 = f2bf(h1);
                const unsigned short lo0 = f2bf(h0 - bf2f(hi0)), lo1 = f2bf(h1 - bf2f(hi1));
                const unsigned int hpack = (unsigned int)hi0 | ((unsigned int)hi1 << 16);
                const unsigned int lpack = (unsigned int)lo0 | ((unsigned int)lo1 << 16);
                const int sw = crow * 512 + ((jc0 ^ (crow & 7)) << 3) + (cp & 3) * 2;
                st4_sc((unsigned int*)&ghh_w[sw], hpack);
                st4_sc((unsigned int*)&ghl_w[sw], lpack);
                if (t >= 1)
                    st4_sc((unsigned int*)&hbuf[(size_t)(t - 1) * (NB * NH) + crow * NH + c0], hpack);
            }

            // ---- drain + ready-flag + (poll while prefetching next xih) ----
            asm volatile("s_waitcnt vmcnt(0)" ::: "memory");
            __syncthreads();   // all threads' h/hbuf stores at the coherence point
            if (tid == 0) {
                unsigned int one = 1u;
                unsigned int* fp = flg + ((size_t)t * 32 + bc) * FLGD;
                asm volatile("global_store_dword %0, %1, off sc0 sc1" :: "v"(fp), "v"(one) : "memory");
            }
            if (t < NT - 1) {
                load_xp(t + 1);            // read-only xih, overlaps the poll window
                if (wv == 0) {
                    const unsigned int* fp = flg + ((size_t)t * 32 + (lane & 31)) * FLGD;
                    while (__hip_atomic_load(fp, __ATOMIC_RELAXED, __HIP_MEMORY_SCOPE_AGENT) == 0u)
                        __builtin_amdgcn_s_sleep(1);
                }
                __syncthreads();           // also drains vmcnt -> DMA count is clean
            }
        }
        asm volatile("s_waitcnt vmcnt(0)" ::: "memory");
        return;
    }

    // ================= streamed phase-C =================
    const int g = blockIdx.x - 32;          // 0..223
    const int jt = g % 79;                  // fixed col tile -> B stays L2-resident
    const int rshare = g / 79;              // 0..2
    const int nshare = (jt < 66) ? 3 : 2;   // blocks sharing this col tile
    const int n0g = jt * 128;
    const int mw2 = (wv >> 2) * 32, nw2 = (wv & 3) * 32;

    unsigned short* __restrict__ AsB = Hhi;          // [2][64*32]
    unsigned short* __restrict__ BsB = Hhi + 4096;   // [2][128*32]

    for (int tt = rshare; tt < NT - 1; tt += nshare) {
        // wait until h(tt+1) stored == hbuf slab tt complete
        if (wv == 0) {
            const unsigned int* fp = flg + ((size_t)(tt + 1) * 32 + (lane & 31)) * FLGD;
            while (__hip_atomic_load(fp, __ATOMIC_RELAXED, __HIP_MEMORY_SCOPE_AGENT) == 0u)
                __builtin_amdgcn_s_sleep(2);
        }
        __syncthreads();

        const unsigned short* __restrict__ hbA = hbuf + (size_t)tt * (NB * NH);
        auto stageC = [&](int buf, int k0) {
            if (tid < 256) {                 // waves 0..3: A (64x32), sc-reads
                const int s = tid;
                const int r = s >> 2, kcol = (s & 3) * 8;
                gl_lds16_sc(hbA + (size_t)r * 512 + k0 + kcol, &AsB[buf * 2048 + s * 8]);
            } else {                         // waves 4..7: B (128x32)
#pragma unroll
                for (int h2 = 0; h2 < 2; ++h2) {
                    const int s = h2 * 256 + (tid - 256);
                    const int r = s >> 2, kcol = (s & 3) * 8;
                    gl_lds16(wlin + (size_t)(n0g + r) * 512 + k0 + kcol, &BsB[buf * 4096 + s * 8]);
                }
            }
        };

        f32x4 acc2[2][2];
#pragma unroll
        for (int i = 0; i < 2; i++)
#pragma unroll
            for (int j = 0; j < 2; j++) acc2[i][j] = (f32x4){0.f, 0.f, 0.f, 0.f};

        stageC(0, 0);
        for (int kt = 0; kt < 16; ++kt) {
            __syncthreads();
            const int cur = kt & 1;
            if (kt < 15) stageC(cur ^ 1, (kt + 1) * 32);
            bf16x8 af[2], bfv[2];
#pragma unroll
            for (int i = 0; i < 2; i++) {
                af[i]  = *(const bf16x8*)&AsB[cur * 2048 + (mw2 + i * 16 + mf) * 32 + kg * 8];
                bfv[i] = *(const bf16x8*)&BsB[cur * 4096 + (nw2 + i * 16 + mf) * 32 + kg * 8];
            }
#pragma unroll
            for (int i = 0; i < 2; i++)
#pragma unroll
                for (int j = 0; j < 2; j++)
                    acc2[i][j] = __builtin_amdgcn_mfma_f32_16x16x32_bf16(af[i], bfv[j], acc2[i][j], 0, 0, 0);
        }
#pragma unroll
        for (int i = 0; i < 2; i++)
#pragma unroll
            for (int j = 0; j < 2; j++) {
                const int col = n0g + nw2 + j * 16 + mf;
                if (col < NV) {
                    const float bl = b_lin[col];
#pragma unroll
                    for (int r = 0; r < 4; r++) {
                        const int b_ = mw2 + i * 16 + kg * 4 + r;   // batch row
                        out[(size_t)b_ * ((NT - 1) * NV) + (size_t)tt * NV + col] = acc2[i][j][r] + bl;
                    }
                }
            }
        __syncthreads();   // tile reads done before next job restages
    }
}

extern "C" void kernel_launch(void* const* d_in, const int* in_sizes, int n_in,
                              void* d_out, int out_size, void* d_ws, size_t ws_size,
                              hipStream_t stream)
{
    const float* features = (const float*)d_in[0];
    const float* cap      = (const float*)d_in[1];
    const float* W_ih     = (const float*)d_in[2];
    const float* W_hh     = (const float*)d_in[3];
    const float* b_ih     = (const float*)d_in[4];
    const float* b_hh     = (const float*)d_in[5];
    const float* W_lin    = (const float*)d_in[6];
    const float* b_lin    = (const float*)d_in[7];
    float* out = (float*)d_out;
    unsigned char* ws = (unsigned char*)d_ws;

    hipMemsetAsync(ws + OFF_C, 0, (size_t)NT * 32 * FLGD * sizeof(unsigned int), stream);

    hipLaunchKernelGGL(prep_kernel, dim3(7722), dim3(256), 0, stream,
                       features, cap, W_ih, W_hh, b_ih, b_hh, W_lin, ws);
    hipLaunchKernelGGL(gemm_a_kernel, dim3(16, 11), dim3(256), 0, stream, ws);
    hipLaunchKernelGGL(fused_persistent, dim3(256), dim3(512), 0, stream, ws, b_lin, out);
}

// Round 4
// 251.048 us; speedup vs baseline: 1.9303x; 1.0270x over previous
//
#include <hip/hip_runtime.h>
#include <hip/hip_bf16.h>

// B=64, T=21, E=H=512, V=10000. fp32 in/out.
// gates = x@W_ih^T + h@W_hh^T + (b_ih+b_hh); i,f,g,o; out = h@W_lin^T + b_lin.

#define NB 64
#define NT 21
#define NE 512
#define NH 512
#define NV 10000
#define G4 2048
#define FLGD 16   // dwords per flag slot (64B line padding)

typedef __attribute__((ext_vector_type(8))) short bf16x8;
typedef __attribute__((ext_vector_type(4))) float f32x4;
typedef __attribute__((ext_vector_type(4))) unsigned short u16x4;

// ---- workspace layout (bytes) ----
#define OFF_WIH_HI   0UL
#define OFF_WIH_LO   2097152UL
#define OFF_WHH_HI   4194304UL     // (unused now; LSTM blocks convert their own W_hh)
#define OFF_WHH_LO   6291456UL     // (unused)
#define OFF_WLIN_HI  8388608UL     // 10112*512*2
#define OFF_XSEQ_HI  18743296UL    // 1408*512*2
#define OFF_XSEQ_LO  20185088UL
#define OFF_BIAS     21626880UL    // 2048*4
#define OFF_XIH      21635072UL    // 21*64*2048*4
#define OFF_GHH      32645120UL    // 2 x 64*512 bf16 h-hi (PRE-SWIZZLED chunk layout)
#define OFF_GHL      32776192UL    // 2 x 64*512 bf16 h-lo (PRE-SWIZZLED chunk layout)
#define OFF_C        32907264UL    // h ready flags: 21 steps x 32 blocks x 64B
#define OFF_HBUF     33038336UL    // 20*64*512 bf16 (sc-visible mid-kernel)
#define OFF_FLG      34349056UL    // xih slab counters: 21 x 64B
// end 34,351,616 B

__device__ inline unsigned short f2bf(float f) {
    unsigned int u = __float_as_uint(f);
    unsigned int r = u + 0x7FFFu + ((u >> 16) & 1u);
    return (unsigned short)(r >> 16);
}
__device__ inline float bf2f(unsigned short s) {
    return __uint_as_float(((unsigned int)s) << 16);
}

__device__ __forceinline__ void gl_lds16(const unsigned short* g, unsigned short* l) {
    auto gp = (const __attribute__((address_space(1))) unsigned int*)(unsigned long long)(const void*)g;
    auto lp = (__attribute__((address_space(3))) unsigned int*)(unsigned int)(unsigned long long)(void*)l;
    __builtin_amdgcn_global_load_lds(gp, lp, 16, 0, 0);
}

// DMA that reads at the coherence point (bypass L1+L2): aux = sc0|sc1 = 1|16.
__device__ __forceinline__ void gl_lds16_sc(const unsigned short* g, unsigned short* l) {
    auto gp = (const __attribute__((address_space(1))) unsigned int*)(unsigned long long)(const void*)g;
    auto lp = (__attribute__((address_space(3))) unsigned int*)(unsigned int)(unsigned long long)(void*)l;
    __builtin_amdgcn_global_load_lds(gp, lp, 16, 0, 17);
}

// Write-through dword store visible at the coherence point.
__device__ __forceinline__ void st4_sc(unsigned int* p, unsigned int v) {
    asm volatile("global_store_dword %0, %1, off sc0 sc1" :: "v"(p), "v"(v) : "memory");
}

// ---------------- prep (vectorized x4; W_hh handled by the fused kernel) ----------------
__global__ __launch_bounds__(256) void prep_kernel(
    const float* __restrict__ features, const float* __restrict__ cap,
    const float* __restrict__ W_ih, const float* __restrict__ b_ih,
    const float* __restrict__ b_hh, const float* __restrict__ W_lin,
    unsigned char* __restrict__ ws)
{
    const int idx = blockIdx.x * 256 + threadIdx.x;
    unsigned short* wih_hi = (unsigned short*)(ws + OFF_WIH_HI);
    unsigned short* wih_lo = (unsigned short*)(ws + OFF_WIH_LO);
    unsigned short* wlin_hi = (unsigned short*)(ws + OFF_WLIN_HI);
    unsigned short* xs_hi = (unsigned short*)(ws + OFF_XSEQ_HI);
    unsigned short* xs_lo = (unsigned short*)(ws + OFF_XSEQ_LO);
    float* bias = (float*)(ws + OFF_BIAS);

    if (idx < 262144) {
        const int i4 = idx * 4;
        float4 w = *(const float4*)(W_ih + i4);
        u16x4 hi, lo;
        hi.x = f2bf(w.x); lo.x = f2bf(w.x - bf2f(hi.x));
        hi.y = f2bf(w.y); lo.y = f2bf(w.y - bf2f(hi.y));
        hi.z = f2bf(w.z); lo.z = f2bf(w.z - bf2f(hi.z));
        hi.w = f2bf(w.w); lo.w = f2bf(w.w - bf2f(hi.w));
        *(u16x4*)(wih_hi + i4) = hi;
        *(u16x4*)(wih_lo + i4) = lo;
    } else if (idx < 1542144) {
        const int i4 = (idx - 262144) * 4;
        float4 w = *(const float4*)(W_lin + i4);
        u16x4 hi;
        hi.x = f2bf(w.x); hi.y = f2bf(w.y); hi.z = f2bf(w.z); hi.w = f2bf(w.w);
        *(u16x4*)(wlin_hi + i4) = hi;
    } else if (idx < 1714176) {
        const int i4 = (idx - 1542144) * 4;
        const int e = i4 & 511;
        const int b = (i4 >> 9) & 63;
        const int t = i4 >> 15;
        float4 x = (t == 0) ? *(const float4*)(features + b * NE + e)
                            : *(const float4*)(cap + b * (NT * NE) + (t - 1) * NE + e);
        u16x4 hi, lo;
        hi.x = f2bf(x.x); lo.x = f2bf(x.x - bf2f(hi.x));
        hi.y = f2bf(x.y); lo.y = f2bf(x.y - bf2f(hi.y));
        hi.z = f2bf(x.z); lo.z = f2bf(x.z - bf2f(hi.z));
        hi.w = f2bf(x.w); lo.w = f2bf(x.w - bf2f(hi.w));
        *(u16x4*)(xs_hi + i4) = hi;
        *(u16x4*)(xs_lo + i4) = lo;
    } else if (idx < 1714688) {
        const int j = (idx - 1714176) * 4;
        float4 a = *(const float4*)(b_ih + j);
        float4 b = *(const float4*)(b_hh + j);
        *(float4*)(bias + j) = make_float4(a.x + b.x, a.y + b.y, a.z + b.z, a.w + b.w);
    }
}

// ---------------- fused persistent ----------------
// Grid = 256 blocks x 512 thr, 147456 B LDS -> 1 block/CU -> all co-resident.
// Blocks 0..31  : LSTM recurrence. Convert OWN W_hh slice from fp32 into
//                 register fragments (no prep dependency); poll xih slab
//                 counter before each load_xp; otherwise as round 3.
// Blocks 32..255: (1) compute the 336 xih tiles (21 slabs x 16 col-tiles,
//                 64x128, 3-pass hi/lo MFMA, identical accumulation order as
//                 the old gemm_a -> bit-identical xih); sc-store + per-slab
//                 ready counter. Early slabs first (tile g, then 224+g).
//                 (2) stream phase-C out-slabs as round 3.
__global__ __launch_bounds__(512) void fused_persistent(
    unsigned char* __restrict__ ws, const float* __restrict__ W_hh_f,
    const float* __restrict__ b_lin, float* __restrict__ out)
{
    __shared__ unsigned short Hhi[64 * 512];   // lstm: h-hi image | workers: GEMM tiles
    __shared__ unsigned short Hlo[64 * 512];   // lstm: h-lo image
    __shared__ float glf[4096];                // lstm: gate values
    const int tid = threadIdx.x;
    const int lane = tid & 63, wv = tid >> 6;
    const int mf = lane & 15, kg = lane >> 4;

    unsigned int* __restrict__ flg = (unsigned int*)(ws + OFF_C);
    unsigned int* __restrict__ slabctr = (unsigned int*)(ws + OFF_FLG);
    unsigned short* __restrict__ hbuf = (unsigned short*)(ws + OFF_HBUF);
    const unsigned short* __restrict__ wlin = (const unsigned short*)(ws + OFF_WLIN_HI);
    const float* __restrict__ bias = (const float*)(ws + OFF_BIAS);
    float* __restrict__ xih_base = (float*)(ws + OFF_XIH);

    if (blockIdx.x < 32) {
        // ================= LSTM recurrence =================
        const int bc = blockIdx.x;
        const int q = wv & 3;        // gate quadrant
        const int mh = wv >> 2;      // row half

        unsigned short* __restrict__ ghh = (unsigned short*)(ws + OFF_GHH);
        unsigned short* __restrict__ ghl = (unsigned short*)(ws + OFF_GHL);

        // ---- convert OWN W_hh slice (fp32 -> hi/lo bf16 fragments) ----
        bf16x8 bh[16], blo[16];
#pragma unroll
        for (int j = 0; j < 16; ++j) {
            const float* src = W_hh_f + (size_t)(q * 512 + bc * 16 + mf) * 512 + j * 32 + kg * 8;
            float4 w0 = *(const float4*)src;
            float4 w1 = *(const float4*)(src + 4);
            float ff[8] = {w0.x, w0.y, w0.z, w0.w, w1.x, w1.y, w1.z, w1.w};
#pragma unroll
            for (int e = 0; e < 8; ++e) {
                const unsigned short h = f2bf(ff[e]);
                bh[j][e] = (short)h;
                blo[j][e] = (short)f2bf(ff[e] - bf2f(h));
            }
        }

        // ---- per-thread cell mapping: 2 ADJACENT cols of one row ----
        const int crow = tid >> 3;           // batch row 0..63
        const int cp = tid & 7;              // col-pair 0..7
        const int c0 = bc * 16 + cp * 2;     // first hidden col
        const int jc0 = c0 >> 3;             // chunk index
        float creg0 = 0.f, creg1 = 0.f;

        float2 xp[4];
        auto load_xp = [&](int tt) {
            const float* __restrict__ xq = xih_base + (size_t)tt * NB * G4;
#pragma unroll
            for (int g2 = 0; g2 < 4; ++g2)
                xp[g2] = *(const float2*)&xq[crow * G4 + g2 * 512 + c0];
        };

        // wait for xih slab 0 (workers produce it), then prefetch
        if (tid == 0) {
            while (__hip_atomic_load(&slabctr[0], __ATOMIC_RELAXED, __HIP_MEMORY_SCOPE_AGENT) < 16u)
                __builtin_amdgcn_s_sleep(1);
        }
        __syncthreads();
        load_xp(0);

        for (int t = 0; t < NT; ++t) {
            f32x4 acc[2];
            acc[0] = (f32x4){0.f, 0.f, 0.f, 0.f};
            acc[1] = (f32x4){0.f, 0.f, 0.f, 0.f};

            if (t > 0) {
                const int rd = (t + 1) & 1;
                const unsigned short* __restrict__ ghh_r = ghh + rd * (NB * NH);
                const unsigned short* __restrict__ ghl_r = ghl + rd * (NB * NH);
                // ---- bulk DMA: 8 hi + 8 lo insts/thread (128 KB), sc-reads ----
#pragma unroll
                for (int i = 0; i < 8; ++i) {
                    const int s = i * 512 + tid;
                    gl_lds16_sc(ghh_r + s * 8, &Hhi[s * 8]);
                }
#pragma unroll
                for (int i = 0; i < 8; ++i) {
                    const int s = i * 512 + tid;
                    gl_lds16_sc(ghl_r + s * 8, &Hlo[s * 8]);
                }
                // hi half done (vmcnt was 0 at loop entry: syncthreads drains)
                asm volatile("s_waitcnt vmcnt(8)" ::: "memory");
                __builtin_amdgcn_s_barrier();
                // ---- hi passes: a_hi x (B_hi + B_lo), lo DMA still streaming ----
#pragma unroll
                for (int kt = 0; kt < 16; ++kt) {
                    const int j = kt * 4 + kg;
#pragma unroll
                    for (int m = 0; m < 2; ++m) {
                        const int row = mh * 32 + m * 16 + mf;
                        bf16x8 a_hi = *(const bf16x8*)&Hhi[(row * 64 + (j ^ (row & 7))) * 8];
                        acc[m] = __builtin_amdgcn_mfma_f32_16x16x32_bf16(a_hi, bh[kt], acc[m], 0, 0, 0);
                        acc[m] = __builtin_amdgcn_mfma_f32_16x16x32_bf16(a_hi, blo[kt], acc[m], 0, 0, 0);
                    }
                }
                asm volatile("s_waitcnt vmcnt(0)" ::: "memory");
                __builtin_amdgcn_s_barrier();
                // ---- lo pass: a_lo x B_hi ----
#pragma unroll
                for (int kt = 0; kt < 16; ++kt) {
                    const int j = kt * 4 + kg;
#pragma unroll
                    for (int m = 0; m < 2; ++m) {
                        const int row = mh * 32 + m * 16 + mf;
                        bf16x8 a_lo = *(const bf16x8*)&Hlo[(row * 64 + (j ^ (row & 7))) * 8];
                        acc[m] = __builtin_amdgcn_mfma_f32_16x16x32_bf16(a_lo, bh[kt], acc[m], 0, 0, 0);
                    }
                }
            }

            // ---- full gate sums straight to LDS ----
#pragma unroll
            for (int m = 0; m < 2; ++m) {
                const int row = mh * 32 + m * 16 + kg * 4;
#pragma unroll
                for (int r = 0; r < 4; ++r)
                    glf[(q * 64 + row + r) * 16 + mf] = acc[m][r];
            }
            __syncthreads();

            // ---- LSTM cell: 2 adjacent cols/thread, packed sc-stores ----
            {
                unsigned short* __restrict__ ghh_w = ghh + (t & 1) * (NB * NH);
                unsigned short* __restrict__ ghl_w = ghl + (t & 1) * (NB * NH);
                const float2 g0 = *(const float2*)&glf[(0 * 64 + crow) * 16 + cp * 2];
                const float2 g1 = *(const float2*)&glf[(1 * 64 + crow) * 16 + cp * 2];
                const float2 g2 = *(const float2*)&glf[(2 * 64 + crow) * 16 + cp * 2];
                const float2 g3 = *(const float2*)&glf[(3 * 64 + crow) * 16 + cp * 2];
                const float gi0 = g0.x + xp[0].x, gi1 = g0.y + xp[0].y;
                const float gf0 = g1.x + xp[1].x, gf1 = g1.y + xp[1].y;
                const float gg0 = g2.x + xp[2].x, gg1 = g2.y + xp[2].y;
                const float go0 = g3.x + xp[3].x, go1 = g3.y + xp[3].y;
                const float i0 = 1.f / (1.f + __expf(-gi0)), i1 = 1.f / (1.f + __expf(-gi1));
                const float f0 = 1.f / (1.f + __expf(-gf0)), f1 = 1.f / (1.f + __expf(-gf1));
                const float ga0 = tanhf(gg0),                ga1 = tanhf(gg1);
                const float o0 = 1.f / (1.f + __expf(-go0)), o1 = 1.f / (1.f + __expf(-go1));
                const float cn0 = f0 * creg0 + i0 * ga0;
                const float cn1 = f1 * creg1 + i1 * ga1;
                creg0 = cn0; creg1 = cn1;
                const float h0 = o0 * tanhf(cn0);
                const float h1 = o1 * tanhf(cn1);
                const unsigned short hi0 = f2bf(h0), hi1 = f2bf(h1);
                const unsigned short lo0 = f2bf(h0 - bf2f(hi0)), lo1 = f2bf(h1 - bf2f(hi1));
                const unsigned int hpack = (unsigned int)hi0 | ((unsigned int)hi1 << 16);
                const unsigned int lpack = (unsigned int)lo0 | ((unsigned int)lo1 << 16);
                const int sw = crow * 512 + ((jc0 ^ (crow & 7)) << 3) + (cp & 3) * 2;
                st4_sc((unsigned int*)&ghh_w[sw], hpack);
                st4_sc((unsigned int*)&ghl_w[sw], lpack);
                if (t >= 1)
                    st4_sc((unsigned int*)&hbuf[(size_t)(t - 1) * (NB * NH) + crow * NH + c0], hpack);
            }

            // ---- drain + ready-flag + slab poll + prefetch + h poll ----
            asm volatile("s_waitcnt vmcnt(0)" ::: "memory");
            __syncthreads();   // all threads' h/hbuf stores at the coherence point
            if (tid == 0) {
                unsigned int one = 1u;
                unsigned int* fp = flg + ((size_t)t * 32 + bc) * FLGD;
                asm volatile("global_store_dword %0, %1, off sc0 sc1" :: "v"(fp), "v"(one) : "memory");
            }
            if (t < NT - 1) {
                if (tid == 0) {
                    while (__hip_atomic_load(&slabctr[(t + 1) * FLGD], __ATOMIC_RELAXED, __HIP_MEMORY_SCOPE_AGENT) < 16u)
                        __builtin_amdgcn_s_sleep(1);
                }
                __syncthreads();           // slab t+1 ready for all threads
                load_xp(t + 1);            // plain loads (first touch after flag)
                if (wv == 0) {
                    const unsigned int* fp = flg + ((size_t)t * 32 + (lane & 31)) * FLGD;
                    while (__hip_atomic_load(fp, __ATOMIC_RELAXED, __HIP_MEMORY_SCOPE_AGENT) == 0u)
                        __builtin_amdgcn_s_sleep(1);
                }
                __syncthreads();           // also drains vmcnt -> DMA count is clean
            }
        }
        asm volatile("s_waitcnt vmcnt(0)" ::: "memory");
        return;
    }

    // ================= workers =================
    const int g = blockIdx.x - 32;          // 0..223
    const int mw2 = (wv >> 2) * 32, nw2 = (wv & 3) * 32;

    // ---- stage 1: xih tiles (old gemm_a), earliest slabs first ----
    {
        const unsigned short* __restrict__ xh = (const unsigned short*)(ws + OFF_XSEQ_HI);
        const unsigned short* __restrict__ xl = (const unsigned short*)(ws + OFF_XSEQ_LO);
        const unsigned short* __restrict__ wih_h = (const unsigned short*)(ws + OFF_WIH_HI);
        const unsigned short* __restrict__ wih_l = (const unsigned short*)(ws + OFF_WIH_LO);

        unsigned short* Ah2 = Hhi;            // [2][2048] shorts
        unsigned short* Al2 = Hhi + 4096;
        unsigned short* Bh2 = Hhi + 8192;     // [2][4096] shorts
        unsigned short* Bl2 = Hhi + 16384;

        const int ntile = (g < 112) ? 2 : 1;
        for (int p = 0; p < ntile; ++p) {
            const int T = (p == 0) ? g : 224 + g;
            const int slab = T >> 4, ct = T & 15;
            const unsigned short* __restrict__ xhA = xh + (size_t)slab * 64 * 512;
            const unsigned short* __restrict__ xlA = xl + (size_t)slab * 64 * 512;

            auto stageA = [&](int buf, int k0) {
                if (tid < 256) {
                    const int s = tid, r = s >> 2, kc = (s & 3) * 8;
                    gl_lds16(xhA + (size_t)r * 512 + k0 + kc, &Ah2[buf * 2048 + s * 8]);
                    gl_lds16(xlA + (size_t)r * 512 + k0 + kc, &Al2[buf * 2048 + s * 8]);
                } else {
#pragma unroll
                    for (int h2 = 0; h2 < 2; ++h2) {
                        const int s = h2 * 256 + (tid - 256), r = s >> 2, kc = (s & 3) * 8;
                        gl_lds16(wih_h + (size_t)(ct * 128 + r) * 512 + k0 + kc, &Bh2[buf * 4096 + s * 8]);
                        gl_lds16(wih_l + (size_t)(ct * 128 + r) * 512 + k0 + kc, &Bl2[buf * 4096 + s * 8]);
                    }
                }
            };

            f32x4 acc2[2][2];
#pragma unroll
            for (int i = 0; i < 2; i++)
#pragma unroll
                for (int j = 0; j < 2; j++) acc2[i][j] = (f32x4){0.f, 0.f, 0.f, 0.f};

            stageA(0, 0);
            for (int kt = 0; kt < 16; ++kt) {
                __syncthreads();
                const int cur = kt & 1;
                if (kt < 15) stageA(cur ^ 1, (kt + 1) * 32);
                bf16x8 ah_[2], al_[2], bh_[2], bl_[2];
#pragma unroll
                for (int i = 0; i < 2; i++) {
                    ah_[i] = *(const bf16x8*)&Ah2[cur * 2048 + (mw2 + i * 16 + mf) * 32 + kg * 8];
                    al_[i] = *(const bf16x8*)&Al2[cur * 2048 + (mw2 + i * 16 + mf) * 32 + kg * 8];
                    bh_[i] = *(const bf16x8*)&Bh2[cur * 4096 + (nw2 + i * 16 + mf) * 32 + kg * 8];
                    bl_[i] = *(const bf16x8*)&Bl2[cur * 4096 + (nw2 + i * 16 + mf) * 32 + kg * 8];
                }
#pragma unroll
                for (int i = 0; i < 2; i++)
#pragma unroll
                    for (int j = 0; j < 2; j++) {
                        acc2[i][j] = __builtin_amdgcn_mfma_f32_16x16x32_bf16(ah_[i], bh_[j], acc2[i][j], 0, 0, 0);
                        acc2[i][j] = __builtin_amdgcn_mfma_f32_16x16x32_bf16(ah_[i], bl_[j], acc2[i][j], 0, 0, 0);
                        acc2[i][j] = __builtin_amdgcn_mfma_f32_16x16x32_bf16(al_[i], bh_[j], acc2[i][j], 0, 0, 0);
                    }
            }
            // epilogue: xih = acc + bias, sc-stores (visible mid-kernel)
#pragma unroll
            for (int i = 0; i < 2; i++)
#pragma unroll
                for (int j = 0; j < 2; j++) {
                    const int col = ct * 128 + nw2 + j * 16 + mf;
                    const float bb = bias[col];
#pragma unroll
                    for (int r = 0; r < 4; r++) {
                        const int row = slab * 64 + mw2 + i * 16 + kg * 4 + r;
                        st4_sc((unsigned int*)&xih_base[(size_t)row * G4 + col],
                               __float_as_uint(acc2[i][j][r] + bb));
                    }
                }
            asm volatile("s_waitcnt vmcnt(0)" ::: "memory");
            __syncthreads();   // all threads' xih stores at the coherence point
            if (tid == 0)
                __hip_atomic_fetch_add(&slabctr[slab * FLGD], 1u, __ATOMIC_RELAXED, __HIP_MEMORY_SCOPE_AGENT);
            __syncthreads();
        }
    }

    // ---- stage 2: streamed phase-C ----
    const int jt = g % 79;                  // fixed col tile -> B stays L2-resident
    const int rshare = g / 79;              // 0..2
    const int nshare = (jt < 66) ? 3 : 2;   // blocks sharing this col tile
    const int n0g = jt * 128;

    unsigned short* __restrict__ AsB = Hhi;          // [2][64*32]
    unsigned short* __restrict__ BsB = Hhi + 4096;   // [2][128*32]

    for (int tt = rshare; tt < NT - 1; tt += nshare) {
        // wait until h(tt+1) stored == hbuf slab tt complete
        if (wv == 0) {
            const unsigned int* fp = flg + ((size_t)(tt + 1) * 32 + (lane & 31)) * FLGD;
            while (__hip_atomic_load(fp, __ATOMIC_RELAXED, __HIP_MEMORY_SCOPE_AGENT) == 0u)
                __builtin_amdgcn_s_sleep(2);
        }
        __syncthreads();

        const unsigned short* __restrict__ hbA = hbuf + (size_t)tt * (NB * NH);
        auto stageC = [&](int buf, int k0) {
            if (tid < 256) {                 // waves 0..3: A (64x32), sc-reads
                const int s = tid;
                const int r = s >> 2, kcol = (s & 3) * 8;
                gl_lds16_sc(hbA + (size_t)r * 512 + k0 + kcol, &AsB[buf * 2048 + s * 8]);
            } else {                         // waves 4..7: B (128x32)
#pragma unroll
                for (int h2 = 0; h2 < 2; ++h2) {
                    const int s = h2 * 256 + (tid - 256);
                    const int r = s >> 2, kcol = (s & 3) * 8;
                    gl_lds16(wlin + (size_t)(n0g + r) * 512 + k0 + kcol, &BsB[buf * 4096 + s * 8]);
                }
            }
        };

        f32x4 acc2[2][2];
#pragma unroll
        for (int i = 0; i < 2; i++)
#pragma unroll
            for (int j = 0; j < 2; j++) acc2[i][j] = (f32x4){0.f, 0.f, 0.f, 0.f};

        stageC(0, 0);
        for (int kt = 0; kt < 16; ++kt) {
            __syncthreads();
            const int cur = kt & 1;
            if (kt < 15) stageC(cur ^ 1, (kt + 1) * 32);
            bf16x8 af[2], bfv[2];
#pragma unroll
            for (int i = 0; i < 2; i++) {
                af[i]  = *(const bf16x8*)&AsB[cur * 2048 + (mw2 + i * 16 + mf) * 32 + kg * 8];
                bfv[i] = *(const bf16x8*)&BsB[cur * 4096 + (nw2 + i * 16 + mf) * 32 + kg * 8];
            }
#pragma unroll
            for (int i = 0; i < 2; i++)
#pragma unroll
                for (int j = 0; j < 2; j++)
                    acc2[i][j] = __builtin_amdgcn_mfma_f32_16x16x32_bf16(af[i], bfv[j], acc2[i][j], 0, 0, 0);
        }
#pragma unroll
        for (int i = 0; i < 2; i++)
#pragma unroll
            for (int j = 0; j < 2; j++) {
                const int col = n0g + nw2 + j * 16 + mf;
                if (col < NV) {
                    const float bl = b_lin[col];
#pragma unroll
                    for (int r = 0; r < 4; r++) {
                        const int b_ = mw2 + i * 16 + kg * 4 + r;   // batch row
                        out[(size_t)b_ * ((NT - 1) * NV) + (size_t)tt * NV + col] = acc2[i][j][r] + bl;
                    }
                }
            }
        __syncthreads();   // tile reads done before next job restages
    }
}

extern "C" void kernel_launch(void* const* d_in, const int* in_sizes, int n_in,
                              void* d_out, int out_size, void* d_ws, size_t ws_size,
                              hipStream_t stream)
{
    const float* features = (const float*)d_in[0];
    const float* cap      = (const float*)d_in[1];
    const float* W_ih     = (const float*)d_in[2];
    const float* W_hh     = (const float*)d_in[3];
    const float* b_ih     = (const float*)d_in[4];
    const float* b_hh     = (const float*)d_in[5];
    const float* W_lin    = (const float*)d_in[6];
    const float* b_lin    = (const float*)d_in[7];
    float* out = (float*)d_out;
    unsigned char* ws = (unsigned char*)d_ws;

    hipMemsetAsync(ws + OFF_C, 0, (size_t)NT * 32 * FLGD * sizeof(unsigned int), stream);
    hipMemsetAsync(ws + OFF_FLG, 0, (size_t)NT * FLGD * sizeof(unsigned int), stream);

    hipLaunchKernelGGL(prep_kernel, dim3(6698), dim3(256), 0, stream,
                       features, cap, W_ih, b_ih, b_hh, W_lin, ws);
    hipLaunchKernelGGL(fused_persistent, dim3(256), dim3(512), 0, stream, ws, W_hh, b_lin, out);
}